// Round 1
// baseline (850.916 us; speedup 1.0000x reference)
//
#include <hip/hip_runtime.h>
#include <stdint.h>

#define NB 2
#define N_ANCHORS 262144           // 2^18
#define LOG2N 18
#define PRE_NMS 6000
#define PROPOSALS 2000
#define NCHUNK 94                  // ceil(6000/64)
#define CAND_CAP 8192
#define PFD 16

// ---- workspace layout (bytes) ----
#define OFF_HISTA 0                                  // 2*65536*4 = 524288
#define OFF_HISTB (512*1024)                         // 524288
#define OFF_SCAL  (1024*1024)                        // 64 B used (zeroed region ends at +256)
#define OFF_CAND  (1024*1024 + 1024)                 // 2*8192*8 = 131072
#define OFF_BOXES (OFF_CAND + 2*CAND_CAP*8)          // 2*6000*16 = 192000
#define OFF_KEEP  (OFF_BOXES + 2*PRE_NMS*16)         // 2*2048*4 = 16384
#define OFF_MASK  (OFF_KEEP + 2*2048*4)              // 2*6000*94*8 = 9024000
// total ~10.4 MB

// scal per batch (8 ints): [0]=T1 [1]=cAbove1 [2]=Kthr [3]=candCount [4]=keptCount

__global__ void hist_hi(const float* __restrict__ probs, unsigned* __restrict__ histA) {
    int i = blockIdx.x * blockDim.x + threadIdx.x;      // 0 .. NB*N-1
    int b = i >> LOG2N;
    unsigned key = __float_as_uint(probs[(size_t)i * 2 + 1]);
    atomicAdd(&histA[b * 65536 + (key >> 16)], 1u);
}

__global__ void hist_lo(const float* __restrict__ probs, const int* __restrict__ scal,
                        unsigned* __restrict__ histB) {
    int i = blockIdx.x * blockDim.x + threadIdx.x;
    int b = i >> LOG2N;
    unsigned key = __float_as_uint(probs[(size_t)i * 2 + 1]);
    if ((int)(key >> 16) == scal[b * 8 + 0])
        atomicAdd(&histB[b * 65536 + (key & 0xFFFFu)], 1u);
}

__global__ __launch_bounds__(1024) void scan_hist(const unsigned* __restrict__ hist,
                                                  int* __restrict__ scal, int level) {
    int b = blockIdx.x;
    const unsigned* h = hist + (size_t)b * 65536;
    int* sc = scal + b * 8;
    unsigned K = (level == 0) ? (unsigned)PRE_NMS : (unsigned)(PRE_NMS - sc[1]);
    int t = threadIdx.x;
    unsigned base = t * 64;
    unsigned s = 0;
    for (int j = 0; j < 64; ++j) s += h[base + j];
    __shared__ unsigned buf[1024];
    buf[t] = s;
    __syncthreads();
    for (int off = 1; off < 1024; off <<= 1) {
        unsigned v = buf[t] + ((t + off < 1024) ? buf[t + off] : 0u);
        __syncthreads();
        buf[t] = v;
        __syncthreads();
    }
    unsigned sufInc = buf[t];           // sum over chunks >= t
    unsigned sufBefore = sufInc - s;    // sum over chunks > t
    if (sufBefore < K && sufInc >= K) { // unique crossing thread
        unsigned run = sufBefore;
        int T = 0;
        for (int j = 63; j >= 0; --j) {
            unsigned c = h[base + j];
            if (run + c >= K) { T = (int)(base + j); break; }
            run += c;
        }
        if (level == 0) { sc[0] = T; sc[1] = (int)run; }
        else            { sc[2] = (int)(((unsigned)sc[0] << 16) | (unsigned)T); }
    }
}

__global__ void compact(const float* __restrict__ probs, int* __restrict__ scal,
                        unsigned long long* __restrict__ cand) {
    int i = blockIdx.x * blockDim.x + threadIdx.x;
    int b = i >> LOG2N;
    int n = i & (N_ANCHORS - 1);
    unsigned key = __float_as_uint(probs[(size_t)i * 2 + 1]);
    unsigned kthr = (unsigned)scal[b * 8 + 2];
    if (key >= kthr) {
        int pos = atomicAdd(&scal[b * 8 + 3], 1);
        if (pos < CAND_CAP)
            cand[(size_t)b * CAND_CAP + pos] =
                ((unsigned long long)key << 32) | (unsigned long long)(~(unsigned)n);
    }
}

__global__ __launch_bounds__(1024) void sort_decode(const unsigned long long* __restrict__ cand,
                                                    const int* __restrict__ scal,
                                                    const float* __restrict__ anchors,
                                                    const float* __restrict__ bbox,
                                                    float4* __restrict__ boxes) {
    __shared__ unsigned long long sh[CAND_CAP];   // 64 KiB
    int b = blockIdx.x, t = threadIdx.x;
    int cnt = scal[b * 8 + 3];
    if (cnt > CAND_CAP) cnt = CAND_CAP;
    for (int s = 0; s < CAND_CAP / 1024; ++s) {
        int i = t + s * 1024;
        sh[i] = (i < cnt) ? cand[(size_t)b * CAND_CAP + i] : 0ull;
    }
    __syncthreads();
    for (int k = 2; k <= CAND_CAP; k <<= 1) {
        for (int j = k >> 1; j > 0; j >>= 1) {
            for (int s = 0; s < CAND_CAP / 1024; ++s) {
                int i = t + s * 1024;
                int l = i ^ j;
                if (l > i) {
                    unsigned long long a = sh[i], c = sh[l];
                    bool desc = ((i & k) == 0);
                    bool sw = desc ? (a < c) : (a > c);
                    if (sw) { sh[i] = c; sh[l] = a; }
                }
            }
            __syncthreads();
        }
    }
    const float4* anch4 = (const float4*)anchors + (size_t)b * N_ANCHORS;
    const float4* bb4   = (const float4*)bbox    + (size_t)b * N_ANCHORS;
    for (int s = 0; s < CAND_CAP / 1024; ++s) {
        int r = t + s * 1024;
        if (r < PRE_NMS) {
            float4 res = make_float4(0.f, 0.f, 0.f, 0.f);
            if (r < cnt) {
                unsigned long long k64 = sh[r];
                int n = (int)(~(unsigned)(k64 & 0xFFFFFFFFull));
                float4 a  = anch4[n];
                float4 dd = bb4[n];
                float d0 = dd.x * 0.1f, d1 = dd.y * 0.1f;
                float d2 = dd.z * 0.2f, d3 = dd.w * 0.2f;
                float h = a.z - a.x, w = a.w - a.y;
                float cy = a.x + 0.5f * h + d0 * h;
                float cx = a.y + 0.5f * w + d1 * w;
                h = h * expf(d2);
                w = w * expf(d3);
                float y1 = cy - 0.5f * h, x1 = cx - 0.5f * w;
                float y2 = y1 + h,        x2 = x1 + w;
                y1 = fminf(fmaxf(y1, 0.f), 1.f);
                x1 = fminf(fmaxf(x1, 0.f), 1.f);
                y2 = fminf(fmaxf(y2, 0.f), 1.f);
                x2 = fminf(fmaxf(x2, 0.f), 1.f);
                res = make_float4(y1, x1, y2, x2);
            }
            boxes[(size_t)b * PRE_NMS + r] = res;
        }
    }
}

__global__ __launch_bounds__(256) void iou_mask(const float4* __restrict__ boxes,
                                                unsigned long long* __restrict__ mask) {
    int c  = blockIdx.x;     // column chunk 0..93
    int rb = blockIdx.y;     // row block
    int b  = blockIdx.z;
    const float4* bx = boxes + (size_t)b * PRE_NMS;
    __shared__ float4 cb[64];
    __shared__ float  ca[64];
    int t = threadIdx.x;
    if (t < 64) {
        int col = c * 64 + t;
        float4 v = (col < PRE_NMS) ? bx[col] : make_float4(0.f, 0.f, 0.f, 0.f);
        cb[t] = v;
        ca[t] = (v.z - v.x) * (v.w - v.y);
    }
    __syncthreads();
    int i = rb * 256 + t;
    if (i < PRE_NMS) {
        float4 bi = bx[i];
        float ai = (bi.z - bi.x) * (bi.w - bi.y);
        unsigned long long m = 0ull;
        #pragma unroll
        for (int j = 0; j < 64; ++j) {
            float4 bj = cb[j];
            float iy1 = fmaxf(bi.x, bj.x);
            float ix1 = fmaxf(bi.y, bj.y);
            float iy2 = fminf(bi.z, bj.z);
            float ix2 = fminf(bi.w, bj.w);
            float inter = fmaxf(iy2 - iy1, 0.f) * fmaxf(ix2 - ix1, 0.f);
            float uni = ai + ca[j] - inter;
            float iou = (uni > 0.f) ? (inter / uni) : 0.f;
            if (iou > 0.7f) m |= (1ull << j);
        }
        mask[((size_t)b * PRE_NMS + i) * NCHUNK + c] = m;
    }
}

__global__ __launch_bounds__(64) void nms_serial(const unsigned long long* __restrict__ mask,
                                                 int* __restrict__ scal,
                                                 int* __restrict__ keepIdx) {
    int b = blockIdx.x;
    int lane = threadIdx.x;
    const unsigned long long* m = mask + (size_t)b * PRE_NMS * NCHUNK;
    int* keep = keepIdx + b * 2048;
    unsigned long long s0 = 0ull, s1 = 0ull;   // lane owns words lane, lane+64
    const bool has1 = lane < (NCHUNK - 64);    // 30 lanes
    unsigned long long A0[PFD], A1[PFD], Nx0[PFD], Nx1[PFD];
    #pragma unroll
    for (int u = 0; u < PFD; ++u) {
        A0[u] = m[(size_t)u * NCHUNK + lane];
        A1[u] = has1 ? m[(size_t)u * NCHUNK + 64 + lane] : 0ull;
        Nx0[u] = 0ull; Nx1[u] = 0ull;
    }
    int kept = 0;
    for (int ib = 0; ib < PRE_NMS; ib += PFD) {
        int nb = ib + PFD;
        if (nb < PRE_NMS) {
            #pragma unroll
            for (int u = 0; u < PFD; ++u) {
                Nx0[u] = m[(size_t)(nb + u) * NCHUNK + lane];
                Nx1[u] = has1 ? m[(size_t)(nb + u) * NCHUNK + 64 + lane] : 0ull;
            }
        }
        #pragma unroll
        for (int u = 0; u < PFD; ++u) {
            int i = ib + u;
            int w = i >> 6, bit = i & 63;
            unsigned long long sw = (w < 64) ? s0 : s1;
            unsigned long long word = __shfl(sw, (w < 64) ? w : (w - 64), 64);
            if (((word >> bit) & 1ull) == 0ull) {   // keep (wave-uniform)
                if (kept < PROPOSALS && lane == 0) keep[kept] = i;
                kept++;
                s0 |= A0[u];
                s1 |= A1[u];
            }
        }
        if (kept >= PROPOSALS) break;
        #pragma unroll
        for (int u = 0; u < PFD; ++u) { A0[u] = Nx0[u]; A1[u] = Nx1[u]; }
    }
    if (lane == 0) scal[b * 8 + 4] = (kept < PROPOSALS) ? kept : PROPOSALS;
}

__global__ void writeout(const float4* __restrict__ boxes, const int* __restrict__ scal,
                         const int* __restrict__ keepIdx, float4* __restrict__ out) {
    int r = blockIdx.x * blockDim.x + threadIdx.x;   // 0 .. NB*PROPOSALS-1
    if (r >= NB * PROPOSALS) return;
    int b = r / PROPOSALS, q = r - b * PROPOSALS;
    int kc = scal[b * 8 + 4];
    float4 v = make_float4(0.f, 0.f, 0.f, 0.f);
    if (q < kc) {
        int i = keepIdx[b * 2048 + q];
        v = boxes[(size_t)b * PRE_NMS + i];
    }
    out[(size_t)b * PROPOSALS + q] = v;
}

extern "C" void kernel_launch(void* const* d_in, const int* in_sizes, int n_in,
                              void* d_out, int out_size, void* d_ws, size_t ws_size,
                              hipStream_t stream) {
    (void)in_sizes; (void)n_in; (void)out_size; (void)ws_size;
    const float* probs   = (const float*)d_in[0];
    const float* bbox    = (const float*)d_in[1];
    const float* anchors = (const float*)d_in[2];
    char* ws = (char*)d_ws;
    unsigned* histA = (unsigned*)(ws + OFF_HISTA);
    unsigned* histB = (unsigned*)(ws + OFF_HISTB);
    int* scal = (int*)(ws + OFF_SCAL);
    unsigned long long* cand = (unsigned long long*)(ws + OFF_CAND);
    float4* boxes = (float4*)(ws + OFF_BOXES);
    int* keepIdx = (int*)(ws + OFF_KEEP);
    unsigned long long* mask = (unsigned long long*)(ws + OFF_MASK);

    // zero histograms + counters (must happen every call: graph replays)
    hipMemsetAsync(ws, 0, OFF_SCAL + 256, stream);

    int total = NB * N_ANCHORS;
    hist_hi<<<total / 256, 256, 0, stream>>>(probs, histA);
    scan_hist<<<NB, 1024, 0, stream>>>(histA, scal, 0);
    hist_lo<<<total / 256, 256, 0, stream>>>(probs, scal, histB);
    scan_hist<<<NB, 1024, 0, stream>>>(histB, scal, 1);
    compact<<<total / 256, 256, 0, stream>>>(probs, scal, cand);
    sort_decode<<<NB, 1024, 0, stream>>>(cand, scal, anchors, bbox, boxes);
    dim3 gIou(NCHUNK, (PRE_NMS + 255) / 256, NB);
    iou_mask<<<gIou, 256, 0, stream>>>(boxes, mask);
    nms_serial<<<NB, 64, 0, stream>>>(mask, scal, keepIdx);
    writeout<<<(NB * PROPOSALS + 255) / 256, 256, 0, stream>>>(boxes, scal, keepIdx, (float4*)d_out);
}

// Round 2
// 646.047 us; speedup vs baseline: 1.3171x; 1.3171x over previous
//
#include <hip/hip_runtime.h>
#include <stdint.h>

typedef unsigned long long u64;

#define NB 2
#define N_ANCHORS 262144           // 2^18
#define LOG2N 18
#define PRE_NMS 6000
#define PROPOSALS 2000
#define NCHUNK 94                  // ceil(6000/64) words per mask row
#define NWIN 94                    // row windows of 64
#define CAND_CAP 8192
#define HBINS 16384                // scores in (0,1) -> key>>16 < 0x3F80 < 16384

// ---- workspace layout (bytes) ----
#define OFF_HIST 0                                  // 2*16384*4 = 131072
#define OFF_SCAL (2*HBINS*4)                        // 131072, 256 B
#define OFF_CAND (OFF_SCAL + 256)                   // 131328, 2*8192*8 = 131072
#define ZERO_BYTES (OFF_CAND + NB*CAND_CAP*8)       // 262400 (memset every call)
#define OFF_BOXES ZERO_BYTES                        // 2*6000*16 = 192000
#define OFF_MASK (OFF_BOXES + NB*PRE_NMS*16)        // 454400 + 9,024,000 ~ 9.5 MB

// scal per batch (8 ints): [2]=kthr(high16<<16) [3]=candCount

__global__ void hist_kernel(const float2* __restrict__ probs2, unsigned* __restrict__ hist) {
    int i = blockIdx.x * blockDim.x + threadIdx.x;      // 0 .. NB*N-1
    int b = i >> LOG2N;
    unsigned key = __float_as_uint(probs2[i].y);
    unsigned bin = key >> 16;
    if (bin > HBINS - 1) bin = HBINS - 1;
    atomicAdd(&hist[b * HBINS + bin], 1u);
}

__global__ __launch_bounds__(1024) void scan_sel(const unsigned* __restrict__ hist,
                                                 int* __restrict__ scal) {
    int b = blockIdx.x;
    const unsigned* h = hist + (size_t)b * HBINS;
    int t = threadIdx.x;
    unsigned base = t * (HBINS / 1024);      // 16 bins/thread
    unsigned s = 0;
    for (int j = 0; j < HBINS / 1024; ++j) s += h[base + j];
    __shared__ unsigned buf[1024];
    buf[t] = s;
    __syncthreads();
    for (int off = 1; off < 1024; off <<= 1) {
        unsigned v = buf[t] + ((t + off < 1024) ? buf[t + off] : 0u);
        __syncthreads();
        buf[t] = v;
        __syncthreads();
    }
    unsigned sufInc = buf[t];           // count of keys with bin >= base
    unsigned sufBefore = sufInc - s;    // count of keys with bin >= base+16
    if (sufBefore < PRE_NMS && sufInc >= PRE_NMS) {   // unique crossing thread
        unsigned run = sufBefore;
        unsigned T = 0;
        for (int j = HBINS / 1024 - 1; j >= 0; --j) {
            unsigned c = h[base + j];
            if (run + c >= PRE_NMS) { T = base + j; break; }
            run += c;
        }
        scal[b * 8 + 2] = (int)(T << 16);   // compact threshold: all keys in bins >= T
    }
}

__global__ void compact(const float2* __restrict__ probs2, int* __restrict__ scal,
                        u64* __restrict__ cand) {
    int i = blockIdx.x * blockDim.x + threadIdx.x;
    int b = i >> LOG2N;
    int n = i & (N_ANCHORS - 1);
    unsigned key = __float_as_uint(probs2[i].y);
    unsigned kthr = (unsigned)scal[b * 8 + 2];
    if (key >= kthr) {
        int pos = atomicAdd(&scal[b * 8 + 3], 1);
        if (pos < CAND_CAP)
            cand[(size_t)b * CAND_CAP + pos] =
                ((u64)key << 32) | (u64)(~(unsigned)n);   // score desc, idx asc
    }
}

// rank-select: each thread owns one candidate, counts strictly-greater keys among
// all 8192 (zero-padded); rank < 6000 -> decode box and scatter to boxes[rank].
__global__ __launch_bounds__(256) void rank_decode(const u64* __restrict__ cand,
                                                   const float* __restrict__ anchors,
                                                   const float* __restrict__ bbox,
                                                   float4* __restrict__ boxes) {
    int b = blockIdx.y;
    int t = threadIdx.x;
    int myIdx = blockIdx.x * 256 + t;                  // 0..8191
    u64 my = cand[(size_t)b * CAND_CAP + myIdx];
    __shared__ u64 sh[2048];
    int rank = 0;
    for (int c = 0; c < CAND_CAP / 2048; ++c) {
        for (int k = 0; k < 8; ++k)
            sh[k * 256 + t] = cand[(size_t)b * CAND_CAP + c * 2048 + k * 256 + t];
        __syncthreads();
        #pragma unroll 8
        for (int j = 0; j < 2048; ++j) rank += (sh[j] > my) ? 1 : 0;
        __syncthreads();
    }
    if (rank < PRE_NMS) {
        int n = (int)(~(unsigned)(my & 0xFFFFFFFFull));
        const float4* anch4 = (const float4*)anchors + (size_t)b * N_ANCHORS;
        const float4* bb4   = (const float4*)bbox    + (size_t)b * N_ANCHORS;
        float4 a  = anch4[n];
        float4 dd = bb4[n];
        float d0 = dd.x * 0.1f, d1 = dd.y * 0.1f;
        float d2 = dd.z * 0.2f, d3 = dd.w * 0.2f;
        float h = a.z - a.x, w = a.w - a.y;
        float cy = a.x + 0.5f * h + d0 * h;
        float cx = a.y + 0.5f * w + d1 * w;
        h = h * expf(d2);
        w = w * expf(d3);
        float y1 = cy - 0.5f * h, x1 = cx - 0.5f * w;
        float y2 = y1 + h,        x2 = x1 + w;
        y1 = fminf(fmaxf(y1, 0.f), 1.f);
        x1 = fminf(fmaxf(x1, 0.f), 1.f);
        y2 = fminf(fmaxf(y2, 0.f), 1.f);
        x2 = fminf(fmaxf(x2, 0.f), 1.f);
        boxes[(size_t)b * PRE_NMS + rank] = make_float4(y1, x1, y2, x2);
    }
}

__global__ __launch_bounds__(256) void iou_mask(const float4* __restrict__ boxes,
                                                u64* __restrict__ mask) {
    int c  = blockIdx.x;     // column chunk 0..93
    int rb = blockIdx.y;     // row block
    int b  = blockIdx.z;
    const float4* bx = boxes + (size_t)b * PRE_NMS;
    __shared__ float4 cb[64];
    __shared__ float  ca[64];
    int t = threadIdx.x;
    if (t < 64) {
        int col = c * 64 + t;
        float4 v = (col < PRE_NMS) ? bx[col] : make_float4(2.f, 2.f, 2.f, 2.f);
        cb[t] = v;
        ca[t] = (v.z - v.x) * (v.w - v.y);
    }
    __syncthreads();
    int i = rb * 256 + t;
    if (i < PRE_NMS) {
        float4 bi = bx[i];
        float ai = (bi.z - bi.x) * (bi.w - bi.y);
        u64 m = 0ull;
        #pragma unroll
        for (int j = 0; j < 64; ++j) {
            float4 bj = cb[j];
            float iy1 = fmaxf(bi.x, bj.x);
            float ix1 = fmaxf(bi.y, bj.y);
            float iy2 = fminf(bi.z, bj.z);
            float ix2 = fminf(bi.w, bj.w);
            float inter = fmaxf(iy2 - iy1, 0.f) * fmaxf(ix2 - ix1, 0.f);
            float uni = ai + ca[j] - inter;
            // iou > 0.7  <=>  inter > 0.7*uni  (uni >= 0 always; uni==0 -> inter==0 -> false)
            if (inter > 0.7f * uni) m |= (1ull << j);
        }
        mask[((size_t)b * PRE_NMS + i) * NCHUNK + c] = m;
    }
}

// Window-parallel greedy NMS: 1 wave/batch. Lane l owns suppressed words l and 64+l.
// Per 64-row window: fetch diagonal block D, compute keep word K (fast path: no
// intra-window forward suppression -> K = ~s[W]), then 64 parallel masked ORs.
__global__ __launch_bounds__(64) void nms_out(const u64* __restrict__ mask,
                                              const float4* __restrict__ boxes,
                                              float4* __restrict__ out) {
    int b = blockIdx.x;
    int lane = threadIdx.x;
    const u64* m = mask + (size_t)b * PRE_NMS * NCHUNK;
    const float4* bx = boxes + (size_t)b * PRE_NMS;
    __shared__ int keepL[PROPOSALS];
    u64 s0 = 0ull, s1 = 0ull;
    const bool has1 = lane < (NCHUNK - 64);    // 30 lanes own a second word
    u64 cur0[16], cur1[16], nxt0[16], nxt1[16];
    #pragma unroll
    for (int u = 0; u < 16; ++u) {             // rows 0..15
        cur0[u] = m[(size_t)u * NCHUNK + lane];
        cur1[u] = has1 ? m[(size_t)u * NCHUNK + 64 + lane] : 0ull;
    }
    u64 D = m[(size_t)lane * NCHUNK + 0];      // window 0 diagonal block
    int kept = 0;
    for (int W = 0; W < NWIN; ++W) {
        int base = W * 64;
        int nrows = PRE_NMS - base; if (nrows > 64) nrows = 64;
        u64 valid = (nrows >= 64) ? ~0ull : ((1ull << nrows) - 1ull);
        u64 sW = (W < 64) ? __shfl(s0, W, 64) : __shfl(s1, W - 64, 64);
        u64 K;
        bool fast = __all((D & ~((2ull << lane) - 1ull)) == 0ull);
        if (fast) {
            K = (~sW) & valid;
        } else {
            u64 run = sW; K = 0ull;
            for (int i = 0; i < nrows; ++i) {
                u64 di = __shfl(D, i, 64);
                if (!((run >> i) & 1ull)) { K |= (1ull << i); run |= di; }
            }
        }
        if ((K >> lane) & 1ull) {
            int rank = __popcll(K & ((1ull << lane) - 1ull));
            int pos = kept + rank;
            if (pos < PROPOSALS) keepL[pos] = base + lane;
        }
        kept += __popcll(K);
        if (kept >= PROPOSALS || W == NWIN - 1) {
            if (kept > PROPOSALS) kept = PROPOSALS;
            break;
        }
        {   // prefetch next window's diagonal block
            int r = base + 64 + lane;
            D = (r < PRE_NMS) ? m[(size_t)r * NCHUNK + (W + 1)] : 0ull;
        }
        // accumulate suppressed |= OR of kept rows, 4 sub-batches of 16 w/ prefetch
        for (int sb = 0; sb < 4; ++sb) {
            int nb = base + (sb + 1) * 16;
            #pragma unroll
            for (int u = 0; u < 16; ++u) {
                int r = nb + u;
                nxt0[u] = (r < PRE_NMS) ? m[(size_t)r * NCHUNK + lane] : 0ull;
                nxt1[u] = (has1 && r < PRE_NMS) ? m[(size_t)r * NCHUNK + 64 + lane] : 0ull;
            }
            #pragma unroll
            for (int u = 0; u < 16; ++u) {
                u64 sel = 0ull - ((K >> (sb * 16 + u)) & 1ull);
                s0 |= cur0[u] & sel;
                s1 |= cur1[u] & sel;
            }
            #pragma unroll
            for (int u = 0; u < 16; ++u) { cur0[u] = nxt0[u]; cur1[u] = nxt1[u]; }
        }
    }
    for (int q = lane; q < PROPOSALS; q += 64) {
        float4 v = make_float4(0.f, 0.f, 0.f, 0.f);
        if (q < kept) v = bx[keepL[q]];
        out[(size_t)b * PROPOSALS + q] = v;
    }
}

extern "C" void kernel_launch(void* const* d_in, const int* in_sizes, int n_in,
                              void* d_out, int out_size, void* d_ws, size_t ws_size,
                              hipStream_t stream) {
    (void)in_sizes; (void)n_in; (void)out_size; (void)ws_size;
    const float2* probs2 = (const float2*)d_in[0];
    const float* bbox    = (const float*)d_in[1];
    const float* anchors = (const float*)d_in[2];
    char* ws = (char*)d_ws;
    unsigned* hist = (unsigned*)(ws + OFF_HIST);
    int* scal = (int*)(ws + OFF_SCAL);
    u64* cand = (u64*)(ws + OFF_CAND);
    float4* boxes = (float4*)(ws + OFF_BOXES);
    u64* mask = (u64*)(ws + OFF_MASK);

    // zero hist + counters + cand (graph replays; stale cand tail would corrupt ranks)
    hipMemsetAsync(ws, 0, ZERO_BYTES, stream);

    int total = NB * N_ANCHORS;
    hist_kernel<<<total / 256, 256, 0, stream>>>(probs2, hist);
    scan_sel<<<NB, 1024, 0, stream>>>(hist, scal);
    compact<<<total / 256, 256, 0, stream>>>(probs2, scal, cand);
    rank_decode<<<dim3(CAND_CAP / 256, NB), 256, 0, stream>>>(cand, anchors, bbox, boxes);
    dim3 gIou(NCHUNK, (PRE_NMS + 255) / 256, NB);
    iou_mask<<<gIou, 256, 0, stream>>>(boxes, mask);
    nms_out<<<NB, 64, 0, stream>>>(mask, boxes, (float4*)d_out);
}

// Round 3
// 390.018 us; speedup vs baseline: 2.1817x; 1.6565x over previous
//
#include <hip/hip_runtime.h>
#include <stdint.h>

typedef unsigned long long u64;

#define NB 2
#define N_ANCHORS 262144           // 2^18
#define LOG2N 18
#define PRE_NMS 6000
#define PROPOSALS 2000
#define NCHUNK 94                  // ceil(6000/64) words per mask row
#define NWIN 94                    // row windows of 64
#define CAND_CAP 8192
#define HBINS 16384                // scores in (0,1) -> key>>16 < 0x3F80 < 16384
#define HB_BLOCKS_PER_B 64
#define HB_CHUNK (N_ANCHORS / HB_BLOCKS_PER_B)   // 4096

// ---- workspace layout (bytes) ----
#define OFF_HIST 0                                  // 2*16384*4 = 131072
#define OFF_SCAL (2*HBINS*4)                        // 131072, 256 B
#define OFF_CAND (OFF_SCAL + 256)                   // 131328, 2*8192*8 = 131072
#define ZERO_BYTES (OFF_CAND + NB*CAND_CAP*8)       // 262400 (memset every call)
#define OFF_BOXES ZERO_BYTES                        // 2*6000*16 = 192000
#define OFF_MASK (OFF_BOXES + NB*PRE_NMS*16)        // 454400 + 9,024,000 ~ 9.5 MB

// scal per batch (8 ints): [2]=kthr(high16<<16) [3]=candCount

// LDS-privatized histogram: one 64KB private histogram per block, merge nonzero bins.
__global__ __launch_bounds__(256) void hist_kernel(const float2* __restrict__ probs2,
                                                   unsigned* __restrict__ hist) {
    __shared__ unsigned lh[HBINS];
    int t = threadIdx.x;
    for (int j = t; j < HBINS; j += 256) lh[j] = 0u;
    __syncthreads();
    int b   = blockIdx.x / HB_BLOCKS_PER_B;
    int blk = blockIdx.x % HB_BLOCKS_PER_B;
    const float2* p = probs2 + (size_t)b * N_ANCHORS + (size_t)blk * HB_CHUNK;
    #pragma unroll 4
    for (int k = 0; k < HB_CHUNK / 256; ++k) {
        unsigned key = __float_as_uint(p[k * 256 + t].y);
        unsigned bin = key >> 16;
        if (bin > HBINS - 1) bin = HBINS - 1;
        atomicAdd(&lh[bin], 1u);
    }
    __syncthreads();
    unsigned* gh = hist + (size_t)b * HBINS;
    for (int j = t; j < HBINS; j += 256) {
        unsigned v = lh[j];
        if (v) atomicAdd(&gh[j], v);
    }
}

__global__ __launch_bounds__(1024) void scan_sel(const unsigned* __restrict__ hist,
                                                 int* __restrict__ scal) {
    int b = blockIdx.x;
    const unsigned* h = hist + (size_t)b * HBINS;
    int t = threadIdx.x;
    unsigned base = t * (HBINS / 1024);      // 16 bins/thread
    unsigned s = 0;
    for (int j = 0; j < HBINS / 1024; ++j) s += h[base + j];
    __shared__ unsigned buf[1024];
    buf[t] = s;
    __syncthreads();
    for (int off = 1; off < 1024; off <<= 1) {
        unsigned v = buf[t] + ((t + off < 1024) ? buf[t + off] : 0u);
        __syncthreads();
        buf[t] = v;
        __syncthreads();
    }
    unsigned sufInc = buf[t];           // count of keys with bin >= base
    unsigned sufBefore = sufInc - s;    // count of keys with bin >= base+16
    if (sufBefore < PRE_NMS && sufInc >= PRE_NMS) {   // unique crossing thread
        unsigned run = sufBefore;
        unsigned T = 0;
        for (int j = HBINS / 1024 - 1; j >= 0; --j) {
            unsigned c = h[base + j];
            if (run + c >= PRE_NMS) { T = base + j; break; }
            run += c;
        }
        scal[b * 8 + 2] = (int)(T << 16);   // compact threshold: all keys in bins >= T
    }
}

// wave-aggregated compaction: one atomic per wave instead of one per passing thread
__global__ void compact(const float2* __restrict__ probs2, int* __restrict__ scal,
                        u64* __restrict__ cand) {
    int i = blockIdx.x * blockDim.x + threadIdx.x;
    int b = i >> LOG2N;                       // uniform within a block
    int n = i & (N_ANCHORS - 1);
    unsigned key = __float_as_uint(probs2[i].y);
    unsigned kthr = (unsigned)scal[b * 8 + 2];
    bool pred = key >= kthr;
    u64 mk = __ballot(pred);
    if (mk) {
        int lane = threadIdx.x & 63;
        int leader = __ffsll((long long)mk) - 1;
        int basePos = 0;
        if (lane == leader) basePos = atomicAdd(&scal[b * 8 + 3], __popcll(mk));
        basePos = __shfl(basePos, leader, 64);
        if (pred) {
            int pos = basePos + __popcll(mk & ((1ull << lane) - 1ull));
            if (pos < CAND_CAP)
                cand[(size_t)b * CAND_CAP + pos] =
                    ((u64)key << 32) | (u64)(~(unsigned)n);   // score desc, idx asc
        }
    }
}

// rank-select: each thread owns one candidate, counts strictly-greater keys among
// all 8192 (zero-padded); rank < 6000 -> decode box and scatter to boxes[rank].
__global__ __launch_bounds__(256) void rank_decode(const u64* __restrict__ cand,
                                                   const float* __restrict__ anchors,
                                                   const float* __restrict__ bbox,
                                                   float4* __restrict__ boxes) {
    int b = blockIdx.y;
    int t = threadIdx.x;
    int myIdx = blockIdx.x * 256 + t;                  // 0..8191
    u64 my = cand[(size_t)b * CAND_CAP + myIdx];
    __shared__ u64 sh[2048];
    int rank = 0;
    for (int c = 0; c < CAND_CAP / 2048; ++c) {
        for (int k = 0; k < 8; ++k)
            sh[k * 256 + t] = cand[(size_t)b * CAND_CAP + c * 2048 + k * 256 + t];
        __syncthreads();
        #pragma unroll 8
        for (int j = 0; j < 2048; ++j) rank += (sh[j] > my) ? 1 : 0;
        __syncthreads();
    }
    if (rank < PRE_NMS) {
        int n = (int)(~(unsigned)(my & 0xFFFFFFFFull));
        const float4* anch4 = (const float4*)anchors + (size_t)b * N_ANCHORS;
        const float4* bb4   = (const float4*)bbox    + (size_t)b * N_ANCHORS;
        float4 a  = anch4[n];
        float4 dd = bb4[n];
        float d0 = dd.x * 0.1f, d1 = dd.y * 0.1f;
        float d2 = dd.z * 0.2f, d3 = dd.w * 0.2f;
        float h = a.z - a.x, w = a.w - a.y;
        float cy = a.x + 0.5f * h + d0 * h;
        float cx = a.y + 0.5f * w + d1 * w;
        h = h * expf(d2);
        w = w * expf(d3);
        float y1 = cy - 0.5f * h, x1 = cx - 0.5f * w;
        float y2 = y1 + h,        x2 = x1 + w;
        y1 = fminf(fmaxf(y1, 0.f), 1.f);
        x1 = fminf(fmaxf(x1, 0.f), 1.f);
        y2 = fminf(fmaxf(y2, 0.f), 1.f);
        x2 = fminf(fmaxf(x2, 0.f), 1.f);
        boxes[(size_t)b * PRE_NMS + rank] = make_float4(y1, x1, y2, x2);
    }
}

__global__ __launch_bounds__(256) void iou_mask(const float4* __restrict__ boxes,
                                                u64* __restrict__ mask) {
    int c  = blockIdx.x;     // column chunk 0..93
    int rb = blockIdx.y;     // row block
    int b  = blockIdx.z;
    const float4* bx = boxes + (size_t)b * PRE_NMS;
    __shared__ float4 cb[64];
    __shared__ float  ca[64];
    int t = threadIdx.x;
    if (t < 64) {
        int col = c * 64 + t;
        float4 v = (col < PRE_NMS) ? bx[col] : make_float4(2.f, 2.f, 2.f, 2.f);
        cb[t] = v;
        ca[t] = (v.z - v.x) * (v.w - v.y);
    }
    __syncthreads();
    int i = rb * 256 + t;
    if (i < PRE_NMS) {
        float4 bi = bx[i];
        float ai = (bi.z - bi.x) * (bi.w - bi.y);
        u64 m = 0ull;
        #pragma unroll
        for (int j = 0; j < 64; ++j) {
            float4 bj = cb[j];
            float iy1 = fmaxf(bi.x, bj.x);
            float ix1 = fmaxf(bi.y, bj.y);
            float iy2 = fminf(bi.z, bj.z);
            float ix2 = fminf(bi.w, bj.w);
            float inter = fmaxf(iy2 - iy1, 0.f) * fmaxf(ix2 - ix1, 0.f);
            float uni = ai + ca[j] - inter;
            // iou > 0.7  <=>  inter > 0.7*uni  (uni >= 0 always; uni==0 -> inter==0 -> false)
            if (inter > 0.7f * uni) m |= (1ull << j);
        }
        mask[((size_t)b * PRE_NMS + i) * NCHUNK + c] = m;
    }
}

// Window-parallel greedy NMS: 1 wave/batch. Lane l owns suppressed words l and 64+l.
__global__ __launch_bounds__(64) void nms_out(const u64* __restrict__ mask,
                                              const float4* __restrict__ boxes,
                                              float4* __restrict__ out) {
    int b = blockIdx.x;
    int lane = threadIdx.x;
    const u64* m = mask + (size_t)b * PRE_NMS * NCHUNK;
    const float4* bx = boxes + (size_t)b * PRE_NMS;
    __shared__ int keepL[PROPOSALS];
    u64 s0 = 0ull, s1 = 0ull;
    const bool has1 = lane < (NCHUNK - 64);    // 30 lanes own a second word
    u64 cur0[16], cur1[16], nxt0[16], nxt1[16];
    #pragma unroll
    for (int u = 0; u < 16; ++u) {             // rows 0..15
        cur0[u] = m[(size_t)u * NCHUNK + lane];
        cur1[u] = has1 ? m[(size_t)u * NCHUNK + 64 + lane] : 0ull;
    }
    u64 D = m[(size_t)lane * NCHUNK + 0];      // window 0 diagonal block
    int kept = 0;
    for (int W = 0; W < NWIN; ++W) {
        int base = W * 64;
        int nrows = PRE_NMS - base; if (nrows > 64) nrows = 64;
        u64 valid = (nrows >= 64) ? ~0ull : ((1ull << nrows) - 1ull);
        u64 sW = (W < 64) ? __shfl(s0, W, 64) : __shfl(s1, W - 64, 64);
        u64 K;
        bool fast = __all((D & ~((2ull << lane) - 1ull)) == 0ull);
        if (fast) {
            K = (~sW) & valid;
        } else {
            u64 run = sW; K = 0ull;
            for (int i = 0; i < nrows; ++i) {
                u64 di = __shfl(D, i, 64);
                if (!((run >> i) & 1ull)) { K |= (1ull << i); run |= di; }
            }
        }
        if ((K >> lane) & 1ull) {
            int rank = __popcll(K & ((1ull << lane) - 1ull));
            int pos = kept + rank;
            if (pos < PROPOSALS) keepL[pos] = base + lane;
        }
        kept += __popcll(K);
        if (kept >= PROPOSALS || W == NWIN - 1) {
            if (kept > PROPOSALS) kept = PROPOSALS;
            break;
        }
        {   // prefetch next window's diagonal block
            int r = base + 64 + lane;
            D = (r < PRE_NMS) ? m[(size_t)r * NCHUNK + (W + 1)] : 0ull;
        }
        // accumulate suppressed |= OR of kept rows, 4 sub-batches of 16 w/ prefetch
        for (int sb = 0; sb < 4; ++sb) {
            int nb = base + (sb + 1) * 16;
            #pragma unroll
            for (int u = 0; u < 16; ++u) {
                int r = nb + u;
                nxt0[u] = (r < PRE_NMS) ? m[(size_t)r * NCHUNK + lane] : 0ull;
                nxt1[u] = (has1 && r < PRE_NMS) ? m[(size_t)r * NCHUNK + 64 + lane] : 0ull;
            }
            #pragma unroll
            for (int u = 0; u < 16; ++u) {
                u64 sel = 0ull - ((K >> (sb * 16 + u)) & 1ull);
                s0 |= cur0[u] & sel;
                s1 |= cur1[u] & sel;
            }
            #pragma unroll
            for (int u = 0; u < 16; ++u) { cur0[u] = nxt0[u]; cur1[u] = nxt1[u]; }
        }
    }
    for (int q = lane; q < PROPOSALS; q += 64) {
        float4 v = make_float4(0.f, 0.f, 0.f, 0.f);
        if (q < kept) v = bx[keepL[q]];
        out[(size_t)b * PROPOSALS + q] = v;
    }
}

extern "C" void kernel_launch(void* const* d_in, const int* in_sizes, int n_in,
                              void* d_out, int out_size, void* d_ws, size_t ws_size,
                              hipStream_t stream) {
    (void)in_sizes; (void)n_in; (void)out_size; (void)ws_size;
    const float2* probs2 = (const float2*)d_in[0];
    const float* bbox    = (const float*)d_in[1];
    const float* anchors = (const float*)d_in[2];
    char* ws = (char*)d_ws;
    unsigned* hist = (unsigned*)(ws + OFF_HIST);
    int* scal = (int*)(ws + OFF_SCAL);
    u64* cand = (u64*)(ws + OFF_CAND);
    float4* boxes = (float4*)(ws + OFF_BOXES);
    u64* mask = (u64*)(ws + OFF_MASK);

    // zero hist + counters + cand (graph replays; stale cand tail would corrupt ranks)
    hipMemsetAsync(ws, 0, ZERO_BYTES, stream);

    int total = NB * N_ANCHORS;
    hist_kernel<<<NB * HB_BLOCKS_PER_B, 256, 0, stream>>>(probs2, hist);
    scan_sel<<<NB, 1024, 0, stream>>>(hist, scal);
    compact<<<total / 256, 256, 0, stream>>>(probs2, scal, cand);
    rank_decode<<<dim3(CAND_CAP / 256, NB), 256, 0, stream>>>(cand, anchors, bbox, boxes);
    dim3 gIou(NCHUNK, (PRE_NMS + 255) / 256, NB);
    iou_mask<<<gIou, 256, 0, stream>>>(boxes, mask);
    nms_out<<<NB, 64, 0, stream>>>(mask, boxes, (float4*)d_out);
}

// Round 4
// 293.559 us; speedup vs baseline: 2.8986x; 1.3286x over previous
//
#include <hip/hip_runtime.h>
#include <stdint.h>

typedef unsigned long long u64;

#define NB 2
#define N_ANCHORS 262144           // 2^18
#define LOG2N 18
#define PRE_NMS 6000
#define PROPOSALS 2000
#define NCHUNK 94                  // ceil(6000/64) words in keep/suppress bitset
#define CAND_CAP 8192
#define HBINS 16384                // scores in (0,1) -> key>>16 < 0x3F80 < 16384
#define HB_BLOCKS_PER_B 64
#define HB_CHUNK (N_ANCHORS / HB_BLOCKS_PER_B)   // 4096
#define EDGE_CAP 65536
#define EDGE_LDS 16384

// ---- workspace layout (bytes) ----
#define OFF_HIST 0                                  // 2*16384*4 = 131072
#define OFF_SCAL (2*HBINS*4)                        // 131072, 256 B
#define OFF_CAND (OFF_SCAL + 256)                   // 131328, 2*8192*8 = 131072
#define ZERO_BYTES (OFF_CAND + NB*CAND_CAP*8)       // 262400 (memset every call)
#define OFF_BOXES ZERO_BYTES                        // 2*6000*16 = 192000
#define OFF_EDGES (OFF_BOXES + NB*PRE_NMS*16)       // 2*65536*4 = 524288 (~1 MB total)

// scal per batch (8 ints): [2]=kthr(high16<<16) [3]=candCount [5]=edgeCount

// LDS-privatized histogram: one 64KB private histogram per block, merge nonzero bins.
__global__ __launch_bounds__(256) void hist_kernel(const float2* __restrict__ probs2,
                                                   unsigned* __restrict__ hist) {
    __shared__ unsigned lh[HBINS];
    int t = threadIdx.x;
    for (int j = t; j < HBINS; j += 256) lh[j] = 0u;
    __syncthreads();
    int b   = blockIdx.x / HB_BLOCKS_PER_B;
    int blk = blockIdx.x % HB_BLOCKS_PER_B;
    const float2* p = probs2 + (size_t)b * N_ANCHORS + (size_t)blk * HB_CHUNK;
    #pragma unroll 4
    for (int k = 0; k < HB_CHUNK / 256; ++k) {
        unsigned key = __float_as_uint(p[k * 256 + t].y);
        unsigned bin = key >> 16;
        if (bin > HBINS - 1) bin = HBINS - 1;
        atomicAdd(&lh[bin], 1u);
    }
    __syncthreads();
    unsigned* gh = hist + (size_t)b * HBINS;
    for (int j = t; j < HBINS; j += 256) {
        unsigned v = lh[j];
        if (v) atomicAdd(&gh[j], v);
    }
}

__global__ __launch_bounds__(1024) void scan_sel(const unsigned* __restrict__ hist,
                                                 int* __restrict__ scal) {
    int b = blockIdx.x;
    const unsigned* h = hist + (size_t)b * HBINS;
    int t = threadIdx.x;
    unsigned base = t * (HBINS / 1024);      // 16 bins/thread
    unsigned s = 0;
    for (int j = 0; j < HBINS / 1024; ++j) s += h[base + j];
    __shared__ unsigned buf[1024];
    buf[t] = s;
    __syncthreads();
    for (int off = 1; off < 1024; off <<= 1) {
        unsigned v = buf[t] + ((t + off < 1024) ? buf[t + off] : 0u);
        __syncthreads();
        buf[t] = v;
        __syncthreads();
    }
    unsigned sufInc = buf[t];           // count of keys with bin >= base
    unsigned sufBefore = sufInc - s;    // count of keys with bin >= base+16
    if (sufBefore < PRE_NMS && sufInc >= PRE_NMS) {   // unique crossing thread
        unsigned run = sufBefore;
        unsigned T = 0;
        for (int j = HBINS / 1024 - 1; j >= 0; --j) {
            unsigned c = h[base + j];
            if (run + c >= PRE_NMS) { T = base + j; break; }
            run += c;
        }
        scal[b * 8 + 2] = (int)(T << 16);   // compact threshold: all keys in bins >= T
    }
}

// wave-aggregated compaction: one atomic per wave instead of one per passing thread
__global__ void compact(const float2* __restrict__ probs2, int* __restrict__ scal,
                        u64* __restrict__ cand) {
    int i = blockIdx.x * blockDim.x + threadIdx.x;
    int b = i >> LOG2N;                       // uniform within a block
    int n = i & (N_ANCHORS - 1);
    unsigned key = __float_as_uint(probs2[i].y);
    unsigned kthr = (unsigned)scal[b * 8 + 2];
    bool pred = key >= kthr;
    u64 mk = __ballot(pred);
    if (mk) {
        int lane = threadIdx.x & 63;
        int leader = __ffsll((long long)mk) - 1;
        int basePos = 0;
        if (lane == leader) basePos = atomicAdd(&scal[b * 8 + 3], __popcll(mk));
        basePos = __shfl(basePos, leader, 64);
        if (pred) {
            int pos = basePos + __popcll(mk & ((1ull << lane) - 1ull));
            if (pos < CAND_CAP)
                cand[(size_t)b * CAND_CAP + pos] =
                    ((u64)key << 32) | (u64)(~(unsigned)n);   // score desc, idx asc
        }
    }
}

// rank-select: each thread owns one candidate, counts strictly-greater keys among
// all 8192 (zero-padded); rank < 6000 -> decode box and scatter to boxes[rank].
__global__ __launch_bounds__(256) void rank_decode(const u64* __restrict__ cand,
                                                   const float* __restrict__ anchors,
                                                   const float* __restrict__ bbox,
                                                   float4* __restrict__ boxes) {
    int b = blockIdx.y;
    int t = threadIdx.x;
    int myIdx = blockIdx.x * 256 + t;                  // 0..8191
    u64 my = cand[(size_t)b * CAND_CAP + myIdx];
    __shared__ u64 sh[2048];
    int rank = 0;
    for (int c = 0; c < CAND_CAP / 2048; ++c) {
        for (int k = 0; k < 8; ++k)
            sh[k * 256 + t] = cand[(size_t)b * CAND_CAP + c * 2048 + k * 256 + t];
        __syncthreads();
        #pragma unroll 8
        for (int j = 0; j < 2048; ++j) rank += (sh[j] > my) ? 1 : 0;
        __syncthreads();
    }
    if (rank < PRE_NMS) {
        int n = (int)(~(unsigned)(my & 0xFFFFFFFFull));
        const float4* anch4 = (const float4*)anchors + (size_t)b * N_ANCHORS;
        const float4* bb4   = (const float4*)bbox    + (size_t)b * N_ANCHORS;
        float4 a  = anch4[n];
        float4 dd = bb4[n];
        float d0 = dd.x * 0.1f, d1 = dd.y * 0.1f;
        float d2 = dd.z * 0.2f, d3 = dd.w * 0.2f;
        float h = a.z - a.x, w = a.w - a.y;
        float cy = a.x + 0.5f * h + d0 * h;
        float cx = a.y + 0.5f * w + d1 * w;
        h = h * expf(d2);
        w = w * expf(d3);
        float y1 = cy - 0.5f * h, x1 = cx - 0.5f * w;
        float y2 = y1 + h,        x2 = x1 + w;
        y1 = fminf(fmaxf(y1, 0.f), 1.f);
        x1 = fminf(fmaxf(x1, 0.f), 1.f);
        y2 = fminf(fmaxf(y2, 0.f), 1.f);
        x2 = fminf(fmaxf(x2, 0.f), 1.f);
        boxes[(size_t)b * PRE_NMS + rank] = make_float4(y1, x1, y2, x2);
    }
}

// Sparse suppression edges: emit (i<j, iou>0.7) pairs. Tiles entirely below the
// diagonal are skipped (only i<j matters).
__global__ __launch_bounds__(256) void iou_edges(const float4* __restrict__ boxes,
                                                 int* __restrict__ scal,
                                                 unsigned* __restrict__ edges) {
    int c  = blockIdx.x;     // column chunk 0..93
    int rb = blockIdx.y;     // row block 0..23
    int b  = blockIdx.z;
    int rowBase = rb * 256;
    if (rowBase >= (c + 1) * 64) return;     // all rows > all cols -> no i<j pairs
    const float4* bx = boxes + (size_t)b * PRE_NMS;
    __shared__ float4 cb[64];
    __shared__ float  ca[64];
    int t = threadIdx.x;
    if (t < 64) {
        int col = c * 64 + t;
        float4 v = (col < PRE_NMS) ? bx[col] : make_float4(2.f, 2.f, 2.f, 2.f);
        cb[t] = v;
        ca[t] = (v.z - v.x) * (v.w - v.y);
    }
    __syncthreads();
    int i = rowBase + t;
    if (i >= PRE_NMS) return;
    // mask of columns with col > i
    int rel = i - c * 64;
    u64 maskGT = (rel < 0) ? ~0ull : ((rel >= 63) ? 0ull : ~((2ull << rel) - 1ull));
    if (!maskGT) return;
    float4 bi = bx[i];
    float ai = (bi.z - bi.x) * (bi.w - bi.y);
    u64 m = 0ull;
    #pragma unroll
    for (int j = 0; j < 64; ++j) {
        float4 bj = cb[j];
        float iy1 = fmaxf(bi.x, bj.x);
        float ix1 = fmaxf(bi.y, bj.y);
        float iy2 = fminf(bi.z, bj.z);
        float ix2 = fminf(bi.w, bj.w);
        float inter = fmaxf(iy2 - iy1, 0.f) * fmaxf(ix2 - ix1, 0.f);
        float uni = ai + ca[j] - inter;
        // iou > 0.7  <=>  inter > 0.7*uni  (uni>=0; uni==0 -> inter==0 -> false)
        if (inter > 0.7f * uni) m |= (1ull << j);
    }
    m &= maskGT;
    while (m) {                               // rare: ~E/6000 per thread
        int j = __ffsll((long long)m) - 1;
        m &= m - 1;
        int col = c * 64 + j;
        int pos = atomicAdd(&scal[b * 8 + 5], 1);
        if (pos < EDGE_CAP)
            edges[(size_t)b * EDGE_CAP + pos] = ((unsigned)col << 16) | (unsigned)i;
    }
}

// Exact greedy NMS as fixpoint of S[j] = exists edge (i,j) with i kept.
// Edges point forward (i<j) -> well-founded -> unique fixpoint = greedy result.
__global__ __launch_bounds__(256) void nms_fix(const unsigned* __restrict__ edges,
                                               const int* __restrict__ scal,
                                               const float4* __restrict__ boxes,
                                               float4* __restrict__ out) {
    int b = blockIdx.x;
    int t = threadIdx.x;
    int E = scal[b * 8 + 5];
    if (E > EDGE_CAP) E = EDGE_CAP;
    __shared__ u64 S[NCHUNK];
    __shared__ u64 Snew[NCHUNK];
    __shared__ unsigned eL[EDGE_LDS];
    __shared__ int changed;
    __shared__ int pref[NCHUNK];
    __shared__ int totalKept;
    const unsigned* eg = edges + (size_t)b * EDGE_CAP;
    bool staged = (E <= EDGE_LDS);
    if (staged) for (int k = t; k < E; k += 256) eL[k] = eg[k];
    for (int w = t; w < NCHUNK; w += 256) S[w] = 0ull;
    __syncthreads();
    if (E > 0) {
        for (int it = 0; it < PRE_NMS + 1; ++it) {
            for (int w = t; w < NCHUNK; w += 256) Snew[w] = 0ull;
            if (t == 0) changed = 0;
            __syncthreads();
            for (int k = t; k < E; k += 256) {
                unsigned e = staged ? eL[k] : eg[k];
                int i = (int)(e & 0xFFFFu), j = (int)(e >> 16);
                if (!((S[i >> 6] >> (i & 63)) & 1ull))
                    atomicOr(&Snew[j >> 6], 1ull << (j & 63));
            }
            __syncthreads();
            int ch = 0;
            for (int w = t; w < NCHUNK; w += 256) {
                if (Snew[w] != S[w]) { ch = 1; S[w] = Snew[w]; }
            }
            if (ch) changed = 1;
            __syncthreads();
            if (!changed) break;
        }
    }
    // keep words + serial prefix (94 popcounts, trivial)
    for (int w = t; w < NCHUNK; w += 256) {
        u64 valid = (w < NCHUNK - 1) ? ~0ull : ((1ull << (PRE_NMS - (NCHUNK - 1) * 64)) - 1ull);
        Snew[w] = (~S[w]) & valid;            // reuse Snew as keep bitset
    }
    __syncthreads();
    if (t == 0) {
        int run = 0;
        for (int w = 0; w < NCHUNK; ++w) { pref[w] = run; run += __popcll(Snew[w]); }
        totalKept = (run < PROPOSALS) ? run : PROPOSALS;
    }
    __syncthreads();
    const float4* bx = boxes + (size_t)b * PRE_NMS;
    float4* ob = out + (size_t)b * PROPOSALS;
    if (t < NCHUNK) {
        u64 k = Snew[t];
        int pos = pref[t];
        while (k && pos < PROPOSALS) {
            int l = __ffsll((long long)k) - 1;
            k &= k - 1;
            ob[pos++] = bx[t * 64 + l];
        }
    }
    int tk = totalKept;
    for (int q = tk + t; q < PROPOSALS; q += 256)
        ob[q] = make_float4(0.f, 0.f, 0.f, 0.f);
}

extern "C" void kernel_launch(void* const* d_in, const int* in_sizes, int n_in,
                              void* d_out, int out_size, void* d_ws, size_t ws_size,
                              hipStream_t stream) {
    (void)in_sizes; (void)n_in; (void)out_size; (void)ws_size;
    const float2* probs2 = (const float2*)d_in[0];
    const float* bbox    = (const float*)d_in[1];
    const float* anchors = (const float*)d_in[2];
    char* ws = (char*)d_ws;
    unsigned* hist = (unsigned*)(ws + OFF_HIST);
    int* scal = (int*)(ws + OFF_SCAL);
    u64* cand = (u64*)(ws + OFF_CAND);
    float4* boxes = (float4*)(ws + OFF_BOXES);
    unsigned* edges = (unsigned*)(ws + OFF_EDGES);

    // zero hist + counters + cand (graph replays; stale cand tail would corrupt ranks)
    hipMemsetAsync(ws, 0, ZERO_BYTES, stream);

    int total = NB * N_ANCHORS;
    hist_kernel<<<NB * HB_BLOCKS_PER_B, 256, 0, stream>>>(probs2, hist);
    scan_sel<<<NB, 1024, 0, stream>>>(hist, scal);
    compact<<<total / 256, 256, 0, stream>>>(probs2, scal, cand);
    rank_decode<<<dim3(CAND_CAP / 256, NB), 256, 0, stream>>>(cand, anchors, bbox, boxes);
    dim3 gIou(NCHUNK, (PRE_NMS + 255) / 256, NB);
    iou_edges<<<gIou, 256, 0, stream>>>(boxes, scal, edges);
    nms_fix<<<NB, 256, 0, stream>>>(edges, scal, boxes, (float4*)d_out);
}

// Round 5
// 198.533 us; speedup vs baseline: 4.2860x; 1.4786x over previous
//
#include <hip/hip_runtime.h>
#include <stdint.h>

typedef unsigned long long u64;

#define NB 2
#define N_ANCHORS 262144           // 2^18
#define LOG2N 18
#define PRE_NMS 6000
#define PROPOSALS 2000
#define NCHUNK 94                  // ceil(6000/64) words in keep/suppress bitset
#define CAND_CAP 8192
#define HBINS 16384                // scores in (0,1) -> key>>16 < 0x3F80 < 16384
#define HB_BLOCKS_PER_B 64
#define HB_CHUNK (N_ANCHORS / HB_BLOCKS_PER_B)   // 4096
#define EDGE_CAP 65536
#define EDGE_LDS 16384

// ---- workspace layout (bytes) ----
#define OFF_HIST 0                                  // 2*16384*4 = 131072 (zeroed)
#define OFF_BCNT (NB*HBINS*4)                       // 131072 (zeroed)
#define OFF_SCAL (2*NB*HBINS*4)                     // 262144, 256 B (zeroed)
#define OFF_CAND (OFF_SCAL + 256)                   // 262400, 131072 (zeroed)
#define ZERO_BYTES (OFF_CAND + NB*CAND_CAP*8)       // 393472
#define OFF_SUFF ZERO_BYTES                         // 131072 (fully overwritten each call)
#define OFF_BOXES (OFF_SUFF + NB*HBINS*4)           // 192000
#define OFF_EDGES (OFF_BOXES + NB*PRE_NMS*16)       // 524288  (~1.24 MB total)

// scal per batch (8 ints): [2]=kthr(high16<<16) [5]=edgeCount

// LDS-privatized histogram: one 64KB private histogram per block, merge nonzero bins.
__global__ __launch_bounds__(256) void hist_kernel(const float2* __restrict__ probs2,
                                                   unsigned* __restrict__ hist) {
    __shared__ unsigned lh[HBINS];
    int t = threadIdx.x;
    for (int j = t; j < HBINS; j += 256) lh[j] = 0u;
    __syncthreads();
    int b   = blockIdx.x / HB_BLOCKS_PER_B;
    int blk = blockIdx.x % HB_BLOCKS_PER_B;
    const float2* p = probs2 + (size_t)b * N_ANCHORS + (size_t)blk * HB_CHUNK;
    #pragma unroll 4
    for (int k = 0; k < HB_CHUNK / 256; ++k) {
        unsigned key = __float_as_uint(p[k * 256 + t].y);
        unsigned bin = key >> 16;
        if (bin > HBINS - 1) bin = HBINS - 1;
        atomicAdd(&lh[bin], 1u);
    }
    __syncthreads();
    unsigned* gh = hist + (size_t)b * HBINS;
    for (int j = t; j < HBINS; j += 256) {
        unsigned v = lh[j];
        if (v) atomicAdd(&gh[j], v);
    }
}

// Threshold select + bin-granular suffix array S[bin] = #keys in bins > bin.
__global__ __launch_bounds__(1024) void scan_sel(const unsigned* __restrict__ hist,
                                                 int* __restrict__ scal,
                                                 unsigned* __restrict__ suff) {
    int b = blockIdx.x;
    const unsigned* h = hist + (size_t)b * HBINS;
    unsigned* sf = suff + (size_t)b * HBINS;
    int t = threadIdx.x;
    unsigned base = t * 16;
    unsigned hl[16];
    unsigned s = 0;
    #pragma unroll
    for (int j = 0; j < 16; ++j) { hl[j] = h[base + j]; s += hl[j]; }
    __shared__ unsigned buf[1024];
    buf[t] = s;
    __syncthreads();
    for (int off = 1; off < 1024; off <<= 1) {
        unsigned v = buf[t] + ((t + off < 1024) ? buf[t + off] : 0u);
        __syncthreads();
        buf[t] = v;
        __syncthreads();
    }
    // buf[k] now = suffix sum over chunks >= k
    unsigned run = (t < 1023) ? buf[t + 1] : 0u;   // keys in chunks > t
    #pragma unroll
    for (int j = 15; j >= 0; --j) {
        sf[base + j] = run;          // strictly-greater-bin count
        run += hl[j];
    }
    unsigned sufInc = buf[t];
    unsigned sufBefore = sufInc - s;
    if (sufBefore < PRE_NMS && sufInc >= PRE_NMS) {   // unique crossing thread
        unsigned r2 = sufBefore;
        unsigned T = 0;
        for (int j = 15; j >= 0; --j) {
            if (r2 + hl[j] >= PRE_NMS) { T = base + j; break; }
            r2 += hl[j];
        }
        scal[b * 8 + 2] = (int)(T << 16);   // compact threshold
    }
}

// Scatter candidates directly to their bin segment: pos = S[bin] + slot.
__global__ void compact(const float2* __restrict__ probs2, const int* __restrict__ scal,
                        const unsigned* __restrict__ suff, unsigned* __restrict__ binCnt,
                        u64* __restrict__ cand) {
    int i = blockIdx.x * blockDim.x + threadIdx.x;
    int b = i >> LOG2N;
    int n = i & (N_ANCHORS - 1);
    unsigned key = __float_as_uint(probs2[i].y);
    unsigned kthr = (unsigned)scal[b * 8 + 2];
    if (key >= kthr) {
        unsigned bin = key >> 16;
        unsigned slot = atomicAdd(&binCnt[(size_t)b * HBINS + bin], 1u);
        unsigned pos = suff[(size_t)b * HBINS + bin] + slot;
        if (pos < CAND_CAP)
            cand[(size_t)b * CAND_CAP + pos] =
                ((u64)key << 32) | (u64)(~(unsigned)n);   // score desc, idx asc
    }
}

// Within-bin rank refinement + box decode. rank = S[bin] + #{segment keys > mine}.
__global__ __launch_bounds__(256) void refine_decode(const u64* __restrict__ cand,
                                                     const unsigned* __restrict__ suff,
                                                     const unsigned* __restrict__ binCnt,
                                                     const float* __restrict__ anchors,
                                                     const float* __restrict__ bbox,
                                                     float4* __restrict__ boxes) {
    int b = blockIdx.y;
    int p = blockIdx.x * 256 + threadIdx.x;            // 0..8191
    u64 my = cand[(size_t)b * CAND_CAP + p];
    if (!my) return;                                   // unused slot (scores > 0 -> key != 0)
    unsigned bin = (unsigned)(my >> 48);
    unsigned s = suff[(size_t)b * HBINS + bin];
    if (s >= PRE_NMS) return;                          // entire segment beyond cutoff
    unsigned c = binCnt[(size_t)b * HBINS + bin];
    if (s + c > CAND_CAP) c = CAND_CAP - s;
    int rank = (int)s;
    const u64* seg = cand + (size_t)b * CAND_CAP + s;
    for (unsigned q = 0; q < c; ++q) rank += (seg[q] > my) ? 1 : 0;
    if (rank < PRE_NMS) {
        int n = (int)(~(unsigned)(my & 0xFFFFFFFFull));
        const float4* anch4 = (const float4*)anchors + (size_t)b * N_ANCHORS;
        const float4* bb4   = (const float4*)bbox    + (size_t)b * N_ANCHORS;
        float4 a  = anch4[n];
        float4 dd = bb4[n];
        float d0 = dd.x * 0.1f, d1 = dd.y * 0.1f;
        float d2 = dd.z * 0.2f, d3 = dd.w * 0.2f;
        float h = a.z - a.x, w = a.w - a.y;
        float cy = a.x + 0.5f * h + d0 * h;
        float cx = a.y + 0.5f * w + d1 * w;
        h = h * expf(d2);
        w = w * expf(d3);
        float y1 = cy - 0.5f * h, x1 = cx - 0.5f * w;
        float y2 = y1 + h,        x2 = x1 + w;
        y1 = fminf(fmaxf(y1, 0.f), 1.f);
        x1 = fminf(fmaxf(x1, 0.f), 1.f);
        y2 = fminf(fmaxf(y2, 0.f), 1.f);
        x2 = fminf(fmaxf(x2, 0.f), 1.f);
        boxes[(size_t)b * PRE_NMS + rank] = make_float4(y1, x1, y2, x2);
    }
}

// Sparse suppression edges: emit (i<j, iou>0.7) pairs; skip tiles fully below diagonal.
__global__ __launch_bounds__(256) void iou_edges(const float4* __restrict__ boxes,
                                                 int* __restrict__ scal,
                                                 unsigned* __restrict__ edges) {
    int c  = blockIdx.x;     // column chunk 0..93
    int rb = blockIdx.y;     // row block 0..23
    int b  = blockIdx.z;
    int rowBase = rb * 256;
    if (rowBase >= (c + 1) * 64) return;     // all rows > all cols -> no i<j pairs
    const float4* bx = boxes + (size_t)b * PRE_NMS;
    __shared__ float4 cb[64];
    __shared__ float  ca[64];
    int t = threadIdx.x;
    if (t < 64) {
        int col = c * 64 + t;
        float4 v = (col < PRE_NMS) ? bx[col] : make_float4(2.f, 2.f, 2.f, 2.f);
        cb[t] = v;
        ca[t] = (v.z - v.x) * (v.w - v.y);
    }
    __syncthreads();
    int i = rowBase + t;
    if (i >= PRE_NMS) return;
    int rel = i - c * 64;
    u64 maskGT = (rel < 0) ? ~0ull : ((rel >= 63) ? 0ull : ~((2ull << rel) - 1ull));
    if (!maskGT) return;
    float4 bi = bx[i];
    float ai = (bi.z - bi.x) * (bi.w - bi.y);
    u64 m = 0ull;
    #pragma unroll
    for (int j = 0; j < 64; ++j) {
        float4 bj = cb[j];
        float iy1 = fmaxf(bi.x, bj.x);
        float ix1 = fmaxf(bi.y, bj.y);
        float iy2 = fminf(bi.z, bj.z);
        float ix2 = fminf(bi.w, bj.w);
        float inter = fmaxf(iy2 - iy1, 0.f) * fmaxf(ix2 - ix1, 0.f);
        float uni = ai + ca[j] - inter;
        // iou > 0.7  <=>  inter > 0.7*uni  (uni>=0; uni==0 -> inter==0 -> false)
        if (inter > 0.7f * uni) m |= (1ull << j);
    }
    m &= maskGT;
    while (m) {                               // rare
        int j = __ffsll((long long)m) - 1;
        m &= m - 1;
        int col = c * 64 + j;
        int pos = atomicAdd(&scal[b * 8 + 5], 1);
        if (pos < EDGE_CAP)
            edges[(size_t)b * EDGE_CAP + pos] = ((unsigned)col << 16) | (unsigned)i;
    }
}

// Exact greedy NMS as fixpoint of S[j] = exists edge (i,j) with i kept.
__global__ __launch_bounds__(256) void nms_fix(const unsigned* __restrict__ edges,
                                               const int* __restrict__ scal,
                                               const float4* __restrict__ boxes,
                                               float4* __restrict__ out) {
    int b = blockIdx.x;
    int t = threadIdx.x;
    int E = scal[b * 8 + 5];
    if (E > EDGE_CAP) E = EDGE_CAP;
    __shared__ u64 S[NCHUNK];
    __shared__ u64 Snew[NCHUNK];
    __shared__ unsigned eL[EDGE_LDS];
    __shared__ int changed;
    __shared__ int pref[NCHUNK];
    __shared__ int totalKept;
    const unsigned* eg = edges + (size_t)b * EDGE_CAP;
    bool staged = (E <= EDGE_LDS);
    if (staged) for (int k = t; k < E; k += 256) eL[k] = eg[k];
    for (int w = t; w < NCHUNK; w += 256) S[w] = 0ull;
    __syncthreads();
    if (E > 0) {
        for (int it = 0; it < PRE_NMS + 1; ++it) {
            for (int w = t; w < NCHUNK; w += 256) Snew[w] = 0ull;
            if (t == 0) changed = 0;
            __syncthreads();
            for (int k = t; k < E; k += 256) {
                unsigned e = staged ? eL[k] : eg[k];
                int i = (int)(e & 0xFFFFu), j = (int)(e >> 16);
                if (!((S[i >> 6] >> (i & 63)) & 1ull))
                    atomicOr(&Snew[j >> 6], 1ull << (j & 63));
            }
            __syncthreads();
            int ch = 0;
            for (int w = t; w < NCHUNK; w += 256) {
                if (Snew[w] != S[w]) { ch = 1; S[w] = Snew[w]; }
            }
            if (ch) changed = 1;
            __syncthreads();
            if (!changed) break;
        }
    }
    for (int w = t; w < NCHUNK; w += 256) {
        u64 valid = (w < NCHUNK - 1) ? ~0ull : ((1ull << (PRE_NMS - (NCHUNK - 1) * 64)) - 1ull);
        Snew[w] = (~S[w]) & valid;            // keep bitset
    }
    __syncthreads();
    if (t == 0) {
        int run = 0;
        for (int w = 0; w < NCHUNK; ++w) { pref[w] = run; run += __popcll(Snew[w]); }
        totalKept = (run < PROPOSALS) ? run : PROPOSALS;
    }
    __syncthreads();
    const float4* bx = boxes + (size_t)b * PRE_NMS;
    float4* ob = out + (size_t)b * PROPOSALS;
    if (t < NCHUNK) {
        u64 k = Snew[t];
        int pos = pref[t];
        while (k && pos < PROPOSALS) {
            int l = __ffsll((long long)k) - 1;
            k &= k - 1;
            ob[pos++] = bx[t * 64 + l];
        }
    }
    int tk = totalKept;
    for (int q = tk + t; q < PROPOSALS; q += 256)
        ob[q] = make_float4(0.f, 0.f, 0.f, 0.f);
}

extern "C" void kernel_launch(void* const* d_in, const int* in_sizes, int n_in,
                              void* d_out, int out_size, void* d_ws, size_t ws_size,
                              hipStream_t stream) {
    (void)in_sizes; (void)n_in; (void)out_size; (void)ws_size;
    const float2* probs2 = (const float2*)d_in[0];
    const float* bbox    = (const float*)d_in[1];
    const float* anchors = (const float*)d_in[2];
    char* ws = (char*)d_ws;
    unsigned* hist   = (unsigned*)(ws + OFF_HIST);
    unsigned* binCnt = (unsigned*)(ws + OFF_BCNT);
    int* scal        = (int*)(ws + OFF_SCAL);
    u64* cand        = (u64*)(ws + OFF_CAND);
    unsigned* suff   = (unsigned*)(ws + OFF_SUFF);
    float4* boxes    = (float4*)(ws + OFF_BOXES);
    unsigned* edges  = (unsigned*)(ws + OFF_EDGES);

    // zero hist + binCnt + counters + cand (graph replays)
    hipMemsetAsync(ws, 0, ZERO_BYTES, stream);

    int total = NB * N_ANCHORS;
    hist_kernel<<<NB * HB_BLOCKS_PER_B, 256, 0, stream>>>(probs2, hist);
    scan_sel<<<NB, 1024, 0, stream>>>(hist, scal, suff);
    compact<<<total / 256, 256, 0, stream>>>(probs2, scal, suff, binCnt, cand);
    refine_decode<<<dim3(CAND_CAP / 256, NB), 256, 0, stream>>>(cand, suff, binCnt,
                                                                anchors, bbox, boxes);
    dim3 gIou(NCHUNK, (PRE_NMS + 255) / 256, NB);
    iou_edges<<<gIou, 256, 0, stream>>>(boxes, scal, edges);
    nms_fix<<<NB, 256, 0, stream>>>(edges, scal, boxes, (float4*)d_out);
}

// Round 6
// 134.566 us; speedup vs baseline: 6.3234x; 1.4754x over previous
//
#include <hip/hip_runtime.h>
#include <stdint.h>

typedef unsigned long long u64;

#define NB 2
#define N_ANCHORS 262144           // 2^18
#define LOG2N 18
#define PRE_NMS 6000
#define PROPOSALS 2000
#define NCHUNK 94                  // ceil(6000/64) words in keep/suppress bitset
#define CAND_CAP 8192
#define HBINS 16384                // scores in (0,1) -> key>>16 < 0x3F80 < 16384
#define HB_BLOCKS_PER_B 64
#define HB_CHUNK (N_ANCHORS / HB_BLOCKS_PER_B)   // 4096
#define EDGE_CAP 65536
#define EDGE_LDS 16384

// ---- workspace layout (bytes) ----
#define OFF_HIST 0                                  // 2*16384*4 = 131072 (zeroed)
#define OFF_BCNT (NB*HBINS*4)                       // 131072 (zeroed)
#define OFF_SCAL (2*NB*HBINS*4)                     // 262144, 256 B (zeroed)
#define OFF_CAND (OFF_SCAL + 256)                   // 262400, 131072 (zeroed)
#define ZERO_BYTES (OFF_CAND + NB*CAND_CAP*8)       // 393472
#define OFF_SUFF ZERO_BYTES                         // 131072 (fully overwritten each call)
#define OFF_BOXES (OFF_SUFF + NB*HBINS*4)           // 192000
#define OFF_EDGES (OFF_BOXES + NB*PRE_NMS*16)       // 524288  (~1.24 MB total)

// scal per batch (8 ints): [2]=kthr(high16<<16) [5]=edgeCount

// LDS-privatized histogram: one 64KB private histogram per block, merge nonzero bins.
__global__ __launch_bounds__(256) void hist_kernel(const float4* __restrict__ probs4,
                                                   unsigned* __restrict__ hist) {
    __shared__ unsigned lh[HBINS];
    int t = threadIdx.x;
    for (int j = t; j < HBINS; j += 256) lh[j] = 0u;
    __syncthreads();
    int b   = blockIdx.x / HB_BLOCKS_PER_B;
    int blk = blockIdx.x % HB_BLOCKS_PER_B;
    // float4 = 2 (prob0, prob1) pairs; keys are .y and .w
    const float4* p = probs4 + ((size_t)b * N_ANCHORS + (size_t)blk * HB_CHUNK) / 2;
    #pragma unroll 4
    for (int k = 0; k < HB_CHUNK / 512; ++k) {
        float4 v = p[k * 256 + t];
        unsigned bin0 = __float_as_uint(v.y) >> 16;
        unsigned bin1 = __float_as_uint(v.w) >> 16;
        if (bin0 > HBINS - 1) bin0 = HBINS - 1;
        if (bin1 > HBINS - 1) bin1 = HBINS - 1;
        atomicAdd(&lh[bin0], 1u);
        atomicAdd(&lh[bin1], 1u);
    }
    __syncthreads();
    unsigned* gh = hist + (size_t)b * HBINS;
    for (int j = t; j < HBINS; j += 256) {
        unsigned v = lh[j];
        if (v) atomicAdd(&gh[j], v);
    }
}

// Threshold select + bin-granular suffix array S[bin] = #keys in bins > bin.
__global__ __launch_bounds__(1024) void scan_sel(const unsigned* __restrict__ hist,
                                                 int* __restrict__ scal,
                                                 unsigned* __restrict__ suff) {
    int b = blockIdx.x;
    const unsigned* h = hist + (size_t)b * HBINS;
    unsigned* sf = suff + (size_t)b * HBINS;
    int t = threadIdx.x;
    unsigned base = t * 16;
    unsigned hl[16];
    unsigned s = 0;
    #pragma unroll
    for (int j = 0; j < 16; ++j) { hl[j] = h[base + j]; s += hl[j]; }
    __shared__ unsigned buf[1024];
    buf[t] = s;
    __syncthreads();
    for (int off = 1; off < 1024; off <<= 1) {
        unsigned v = buf[t] + ((t + off < 1024) ? buf[t + off] : 0u);
        __syncthreads();
        buf[t] = v;
        __syncthreads();
    }
    // buf[k] now = suffix sum over chunks >= k
    unsigned run = (t < 1023) ? buf[t + 1] : 0u;   // keys in chunks > t
    #pragma unroll
    for (int j = 15; j >= 0; --j) {
        sf[base + j] = run;          // strictly-greater-bin count
        run += hl[j];
    }
    unsigned sufInc = buf[t];
    unsigned sufBefore = sufInc - s;
    if (sufBefore < PRE_NMS && sufInc >= PRE_NMS) {   // unique crossing thread
        unsigned r2 = sufBefore;
        unsigned T = 0;
        for (int j = 15; j >= 0; --j) {
            if (r2 + hl[j] >= PRE_NMS) { T = base + j; break; }
            r2 += hl[j];
        }
        scal[b * 8 + 2] = (int)(T << 16);   // compact threshold
    }
}

// Scatter candidates directly to their bin segment: pos = S[bin] + slot.
__global__ void compact(const float2* __restrict__ probs2, const int* __restrict__ scal,
                        const unsigned* __restrict__ suff, unsigned* __restrict__ binCnt,
                        u64* __restrict__ cand) {
    int i = blockIdx.x * blockDim.x + threadIdx.x;
    int b = i >> LOG2N;
    int n = i & (N_ANCHORS - 1);
    unsigned key = __float_as_uint(probs2[i].y);
    unsigned kthr = (unsigned)scal[b * 8 + 2];
    if (key >= kthr) {
        unsigned bin = key >> 16;
        unsigned slot = atomicAdd(&binCnt[(size_t)b * HBINS + bin], 1u);
        unsigned pos = suff[(size_t)b * HBINS + bin] + slot;
        if (pos < CAND_CAP)
            cand[(size_t)b * CAND_CAP + pos] =
                ((u64)key << 32) | (u64)(~(unsigned)n);   // score desc, idx asc
    }
}

// Wave-cooperative within-bin ranking + decode: one 64-lane wave per candidate.
// Lanes stride the bin segment (coalesced); 6-step shfl reduce; lane 0 decodes.
__global__ __launch_bounds__(256) void refine_decode(const u64* __restrict__ cand,
                                                     const unsigned* __restrict__ suff,
                                                     const unsigned* __restrict__ binCnt,
                                                     const float* __restrict__ anchors,
                                                     const float* __restrict__ bbox,
                                                     float4* __restrict__ boxes) {
    int b = blockIdx.y;
    int wave = threadIdx.x >> 6;
    int lane = threadIdx.x & 63;
    int p = blockIdx.x * 4 + wave;                     // candidate slot 0..8191
    u64 my = cand[(size_t)b * CAND_CAP + p];           // wave-uniform broadcast
    if (!my) return;                                   // unused slot (scores>0 -> key!=0)
    unsigned bin = (unsigned)(my >> 48);
    unsigned s = suff[(size_t)b * HBINS + bin];
    if (s >= PRE_NMS) return;                          // entire segment beyond cutoff
    unsigned c = binCnt[(size_t)b * HBINS + bin];
    if (s + c > CAND_CAP) c = CAND_CAP - s;
    const u64* seg = cand + (size_t)b * CAND_CAP + s;
    int cnt = 0;
    for (unsigned q = lane; q < c; q += 64)            // coalesced 512B/iter
        cnt += (seg[q] > my) ? 1 : 0;
    #pragma unroll
    for (int off = 32; off; off >>= 1) cnt += __shfl_down(cnt, off, 64);
    int rank = (int)s + __shfl(cnt, 0, 64);
    if (rank < PRE_NMS && lane == 0) {
        int n = (int)(~(unsigned)(my & 0xFFFFFFFFull));
        const float4* anch4 = (const float4*)anchors + (size_t)b * N_ANCHORS;
        const float4* bb4   = (const float4*)bbox    + (size_t)b * N_ANCHORS;
        float4 a  = anch4[n];
        float4 dd = bb4[n];
        float d0 = dd.x * 0.1f, d1 = dd.y * 0.1f;
        float d2 = dd.z * 0.2f, d3 = dd.w * 0.2f;
        float h = a.z - a.x, w = a.w - a.y;
        float cy = a.x + 0.5f * h + d0 * h;
        float cx = a.y + 0.5f * w + d1 * w;
        h = h * expf(d2);
        w = w * expf(d3);
        float y1 = cy - 0.5f * h, x1 = cx - 0.5f * w;
        float y2 = y1 + h,        x2 = x1 + w;
        y1 = fminf(fmaxf(y1, 0.f), 1.f);
        x1 = fminf(fmaxf(x1, 0.f), 1.f);
        y2 = fminf(fmaxf(y2, 0.f), 1.f);
        x2 = fminf(fmaxf(x2, 0.f), 1.f);
        boxes[(size_t)b * PRE_NMS + rank] = make_float4(y1, x1, y2, x2);
    }
}

// Sparse suppression edges: emit (i<j, iou>0.7) pairs; skip tiles fully below diagonal.
__global__ __launch_bounds__(256) void iou_edges(const float4* __restrict__ boxes,
                                                 int* __restrict__ scal,
                                                 unsigned* __restrict__ edges) {
    int c  = blockIdx.x;     // column chunk 0..93
    int rb = blockIdx.y;     // row block 0..23
    int b  = blockIdx.z;
    int rowBase = rb * 256;
    if (rowBase >= (c + 1) * 64) return;     // all rows > all cols -> no i<j pairs
    const float4* bx = boxes + (size_t)b * PRE_NMS;
    __shared__ float4 cb[64];
    __shared__ float  ca[64];
    int t = threadIdx.x;
    if (t < 64) {
        int col = c * 64 + t;
        float4 v = (col < PRE_NMS) ? bx[col] : make_float4(2.f, 2.f, 2.f, 2.f);
        cb[t] = v;
        ca[t] = (v.z - v.x) * (v.w - v.y);
    }
    __syncthreads();
    int i = rowBase + t;
    if (i >= PRE_NMS) return;
    int rel = i - c * 64;
    u64 maskGT = (rel < 0) ? ~0ull : ((rel >= 63) ? 0ull : ~((2ull << rel) - 1ull));
    if (!maskGT) return;
    float4 bi = bx[i];
    float ai = (bi.z - bi.x) * (bi.w - bi.y);
    u64 m = 0ull;
    #pragma unroll
    for (int j = 0; j < 64; ++j) {
        float4 bj = cb[j];
        float iy1 = fmaxf(bi.x, bj.x);
        float ix1 = fmaxf(bi.y, bj.y);
        float iy2 = fminf(bi.z, bj.z);
        float ix2 = fminf(bi.w, bj.w);
        float inter = fmaxf(iy2 - iy1, 0.f) * fmaxf(ix2 - ix1, 0.f);
        float uni = ai + ca[j] - inter;
        // iou > 0.7  <=>  inter > 0.7*uni  (uni>=0; uni==0 -> inter==0 -> false)
        if (inter > 0.7f * uni) m |= (1ull << j);
    }
    m &= maskGT;
    while (m) {                               // rare
        int j = __ffsll((long long)m) - 1;
        m &= m - 1;
        int col = c * 64 + j;
        int pos = atomicAdd(&scal[b * 8 + 5], 1);
        if (pos < EDGE_CAP)
            edges[(size_t)b * EDGE_CAP + pos] = ((unsigned)col << 16) | (unsigned)i;
    }
}

// Exact greedy NMS as fixpoint of S[j] = exists edge (i,j) with i kept.
__global__ __launch_bounds__(256) void nms_fix(const unsigned* __restrict__ edges,
                                               const int* __restrict__ scal,
                                               const float4* __restrict__ boxes,
                                               float4* __restrict__ out) {
    int b = blockIdx.x;
    int t = threadIdx.x;
    int E = scal[b * 8 + 5];
    if (E > EDGE_CAP) E = EDGE_CAP;
    __shared__ u64 S[NCHUNK];
    __shared__ u64 Snew[NCHUNK];
    __shared__ unsigned eL[EDGE_LDS];
    __shared__ int changed;
    __shared__ int pref[NCHUNK];
    __shared__ int totalKept;
    const unsigned* eg = edges + (size_t)b * EDGE_CAP;
    bool staged = (E <= EDGE_LDS);
    if (staged) for (int k = t; k < E; k += 256) eL[k] = eg[k];
    for (int w = t; w < NCHUNK; w += 256) S[w] = 0ull;
    __syncthreads();
    if (E > 0) {
        for (int it = 0; it < PRE_NMS + 1; ++it) {
            for (int w = t; w < NCHUNK; w += 256) Snew[w] = 0ull;
            if (t == 0) changed = 0;
            __syncthreads();
            for (int k = t; k < E; k += 256) {
                unsigned e = staged ? eL[k] : eg[k];
                int i = (int)(e & 0xFFFFu), j = (int)(e >> 16);
                if (!((S[i >> 6] >> (i & 63)) & 1ull))
                    atomicOr(&Snew[j >> 6], 1ull << (j & 63));
            }
            __syncthreads();
            int ch = 0;
            for (int w = t; w < NCHUNK; w += 256) {
                if (Snew[w] != S[w]) { ch = 1; S[w] = Snew[w]; }
            }
            if (ch) changed = 1;
            __syncthreads();
            if (!changed) break;
        }
    }
    for (int w = t; w < NCHUNK; w += 256) {
        u64 valid = (w < NCHUNK - 1) ? ~0ull : ((1ull << (PRE_NMS - (NCHUNK - 1) * 64)) - 1ull);
        Snew[w] = (~S[w]) & valid;            // keep bitset
    }
    __syncthreads();
    if (t == 0) {
        int run = 0;
        for (int w = 0; w < NCHUNK; ++w) { pref[w] = run; run += __popcll(Snew[w]); }
        totalKept = (run < PROPOSALS) ? run : PROPOSALS;
    }
    __syncthreads();
    const float4* bx = boxes + (size_t)b * PRE_NMS;
    float4* ob = out + (size_t)b * PROPOSALS;
    if (t < NCHUNK) {
        u64 k = Snew[t];
        int pos = pref[t];
        while (k && pos < PROPOSALS) {
            int l = __ffsll((long long)k) - 1;
            k &= k - 1;
            ob[pos++] = bx[t * 64 + l];
        }
    }
    int tk = totalKept;
    for (int q = tk + t; q < PROPOSALS; q += 256)
        ob[q] = make_float4(0.f, 0.f, 0.f, 0.f);
}

extern "C" void kernel_launch(void* const* d_in, const int* in_sizes, int n_in,
                              void* d_out, int out_size, void* d_ws, size_t ws_size,
                              hipStream_t stream) {
    (void)in_sizes; (void)n_in; (void)out_size; (void)ws_size;
    const float2* probs2 = (const float2*)d_in[0];
    const float* bbox    = (const float*)d_in[1];
    const float* anchors = (const float*)d_in[2];
    char* ws = (char*)d_ws;
    unsigned* hist   = (unsigned*)(ws + OFF_HIST);
    unsigned* binCnt = (unsigned*)(ws + OFF_BCNT);
    int* scal        = (int*)(ws + OFF_SCAL);
    u64* cand        = (u64*)(ws + OFF_CAND);
    unsigned* suff   = (unsigned*)(ws + OFF_SUFF);
    float4* boxes    = (float4*)(ws + OFF_BOXES);
    unsigned* edges  = (unsigned*)(ws + OFF_EDGES);

    // zero hist + binCnt + counters + cand (graph replays)
    hipMemsetAsync(ws, 0, ZERO_BYTES, stream);

    int total = NB * N_ANCHORS;
    hist_kernel<<<NB * HB_BLOCKS_PER_B, 256, 0, stream>>>((const float4*)probs2, hist);
    scan_sel<<<NB, 1024, 0, stream>>>(hist, scal, suff);
    compact<<<total / 256, 256, 0, stream>>>(probs2, scal, suff, binCnt, cand);
    refine_decode<<<dim3(CAND_CAP / 4, NB), 256, 0, stream>>>(cand, suff, binCnt,
                                                              anchors, bbox, boxes);
    dim3 gIou(NCHUNK, (PRE_NMS + 255) / 256, NB);
    iou_edges<<<gIou, 256, 0, stream>>>(boxes, scal, edges);
    nms_fix<<<NB, 256, 0, stream>>>(edges, scal, boxes, (float4*)d_out);
}

// Round 7
// 82.518 us; speedup vs baseline: 10.3119x; 1.6307x over previous
//
#include <hip/hip_runtime.h>
#include <stdint.h>

typedef unsigned long long u64;

#define NB 2
#define N_ANCHORS 262144           // 2^18
#define LOG2N 18
#define PRE_NMS 6000
#define PROPOSALS 2000
#define NCHUNK 94                  // ceil(6000/64) words in keep/suppress bitset
#define CAND_CAP 8192
#define HBINS 16384                // scores in (0,1) -> key>>16 < 0x3F80 < 16384
#define HB_BLOCKS_PER_B 64
#define HB_CHUNK (N_ANCHORS / HB_BLOCKS_PER_B)   // 4096
#define CB_BLOCKS_PER_B 64
#define CB_CHUNK (N_ANCHORS / CB_BLOCKS_PER_B)   // 4096
#define CBUF 512
#define EDGE_CAP 65536
#define EDGE_LDS 16384

// ---- workspace layout (bytes) ----
#define OFF_HIST 0                                  // 2*16384*4 = 131072 (zeroed)
#define OFF_BCNT (NB*HBINS*4)                       // 131072 (zeroed)
#define OFF_SCAL (2*NB*HBINS*4)                     // 262144, 256 B (zeroed)
#define OFF_CAND (OFF_SCAL + 256)                   // 262400, 131072 (zeroed)
#define ZERO_BYTES (OFF_CAND + NB*CAND_CAP*8)       // 393472
#define OFF_SUFF ZERO_BYTES                         // 131072 (fully overwritten each call)
#define OFF_BOXES (OFF_SUFF + NB*HBINS*4)           // 192000
#define OFF_EDGES (OFF_BOXES + NB*PRE_NMS*16)       // 524288  (~1.24 MB total)

// scal per batch (8 ints): [2]=kthr(high16<<16) [5]=edgeCount

// LDS-privatized histogram: one 64KB private histogram per block, merge nonzero bins.
__global__ __launch_bounds__(256) void hist_kernel(const float4* __restrict__ probs4,
                                                   unsigned* __restrict__ hist) {
    __shared__ unsigned lh[HBINS];
    int t = threadIdx.x;
    for (int j = t; j < HBINS; j += 256) lh[j] = 0u;
    __syncthreads();
    int b   = blockIdx.x / HB_BLOCKS_PER_B;
    int blk = blockIdx.x % HB_BLOCKS_PER_B;
    // float4 = 2 (prob0, prob1) pairs; keys are .y and .w
    const float4* p = probs4 + ((size_t)b * N_ANCHORS + (size_t)blk * HB_CHUNK) / 2;
    #pragma unroll 4
    for (int k = 0; k < HB_CHUNK / 512; ++k) {
        float4 v = p[k * 256 + t];
        unsigned bin0 = __float_as_uint(v.y) >> 16;
        unsigned bin1 = __float_as_uint(v.w) >> 16;
        if (bin0 > HBINS - 1) bin0 = HBINS - 1;
        if (bin1 > HBINS - 1) bin1 = HBINS - 1;
        atomicAdd(&lh[bin0], 1u);
        atomicAdd(&lh[bin1], 1u);
    }
    __syncthreads();
    unsigned* gh = hist + (size_t)b * HBINS;
    for (int j = t; j < HBINS; j += 256) {
        unsigned v = lh[j];
        if (v) atomicAdd(&gh[j], v);
    }
}

// Threshold select + bin-granular suffix array S[bin] = #keys in bins > bin.
__global__ __launch_bounds__(1024) void scan_sel(const unsigned* __restrict__ hist,
                                                 int* __restrict__ scal,
                                                 unsigned* __restrict__ suff) {
    int b = blockIdx.x;
    const unsigned* h = hist + (size_t)b * HBINS;
    unsigned* sf = suff + (size_t)b * HBINS;
    int t = threadIdx.x;
    unsigned base = t * 16;
    unsigned hl[16];
    unsigned s = 0;
    #pragma unroll
    for (int j = 0; j < 16; ++j) { hl[j] = h[base + j]; s += hl[j]; }
    __shared__ unsigned buf[1024];
    buf[t] = s;
    __syncthreads();
    for (int off = 1; off < 1024; off <<= 1) {
        unsigned v = buf[t] + ((t + off < 1024) ? buf[t + off] : 0u);
        __syncthreads();
        buf[t] = v;
        __syncthreads();
    }
    // buf[k] now = suffix sum over chunks >= k
    unsigned run = (t < 1023) ? buf[t + 1] : 0u;   // keys in chunks > t
    #pragma unroll
    for (int j = 15; j >= 0; --j) {
        sf[base + j] = run;          // strictly-greater-bin count
        run += hl[j];
    }
    unsigned sufInc = buf[t];
    unsigned sufBefore = sufInc - s;
    if (sufBefore < PRE_NMS && sufInc >= PRE_NMS) {   // unique crossing thread
        unsigned r2 = sufBefore;
        unsigned T = 0;
        for (int j = 15; j >= 0; --j) {
            if (r2 + hl[j] >= PRE_NMS) { T = base + j; break; }
            r2 += hl[j];
        }
        scal[b * 8 + 2] = (int)(T << 16);   // compact threshold
    }
}

// LDS-privatized compaction: per-block slot allocation in LDS, one global
// atomicAdd per (block, nonzero bin), then scatter to cand[suff+base+slot].
__global__ __launch_bounds__(256) void compact(const float4* __restrict__ probs4,
                                               const int* __restrict__ scal,
                                               const unsigned* __restrict__ suff,
                                               unsigned* __restrict__ binCnt,
                                               u64* __restrict__ cand) {
    __shared__ unsigned lcnt[HBINS];     // pass A: local count; pass B: global base
    __shared__ u64 keyBuf[CBUF];
    __shared__ unsigned slotBuf[CBUF];
    __shared__ int nc;
    int t = threadIdx.x;
    int b   = blockIdx.x / CB_BLOCKS_PER_B;
    int blk = blockIdx.x % CB_BLOCKS_PER_B;
    for (int j = t; j < HBINS; j += 256) lcnt[j] = 0u;
    if (t == 0) nc = 0;
    __syncthreads();
    unsigned kthr = (unsigned)scal[b * 8 + 2];
    const unsigned* sfB = suff + (size_t)b * HBINS;
    unsigned* bcB = binCnt + (size_t)b * HBINS;
    u64* candB = cand + (size_t)b * CAND_CAP;
    size_t anchor0 = (size_t)blk * CB_CHUNK;
    const float4* p = probs4 + ((size_t)b * N_ANCHORS + anchor0) / 2;
    #pragma unroll 2
    for (int k = 0; k < CB_CHUNK / 512; ++k) {
        float4 v = p[k * 256 + t];
        unsigned n0 = (unsigned)(anchor0 + ((size_t)(k * 256 + t)) * 2);
        unsigned keys[2] = { __float_as_uint(v.y), __float_as_uint(v.w) };
        #pragma unroll
        for (int e = 0; e < 2; ++e) {
            unsigned key = keys[e];
            if (key >= kthr) {
                unsigned bin = key >> 16;
                u64 k64 = ((u64)key << 32) | (u64)(~(n0 + e));
                int idx = atomicAdd(&nc, 1);
                if (idx < CBUF) {
                    unsigned slot = atomicAdd(&lcnt[bin], 1u);
                    keyBuf[idx] = k64;
                    slotBuf[idx] = slot;
                } else {   // overflow fallback: direct global allocation (correct, slow)
                    unsigned gs = atomicAdd(&bcB[bin], 1u);
                    unsigned pos = sfB[bin] + gs;
                    if (pos < CAND_CAP) candB[pos] = k64;
                }
            }
        }
    }
    __syncthreads();
    for (int j = t; j < HBINS; j += 256) {     // pass B: merge, lcnt <- global base
        unsigned c = lcnt[j];
        if (c) lcnt[j] = atomicAdd(&bcB[j], c);
    }
    __syncthreads();
    int tot = nc < CBUF ? nc : CBUF;           // pass C: scatter
    for (int k = t; k < tot; k += 256) {
        u64 k64 = keyBuf[k];
        unsigned bin = (unsigned)(k64 >> 48);
        unsigned pos = sfB[bin] + lcnt[bin] + slotBuf[k];
        if (pos < CAND_CAP) candB[pos] = k64;
    }
}

// Wave-cooperative within-bin ranking + decode: one 64-lane wave per candidate.
__global__ __launch_bounds__(256) void refine_decode(const u64* __restrict__ cand,
                                                     const unsigned* __restrict__ suff,
                                                     const unsigned* __restrict__ binCnt,
                                                     const float* __restrict__ anchors,
                                                     const float* __restrict__ bbox,
                                                     float4* __restrict__ boxes) {
    int b = blockIdx.y;
    int wave = threadIdx.x >> 6;
    int lane = threadIdx.x & 63;
    int p = blockIdx.x * 4 + wave;                     // candidate slot 0..8191
    u64 my = cand[(size_t)b * CAND_CAP + p];           // wave-uniform broadcast
    if (!my) return;                                   // unused slot (scores>0 -> key!=0)
    unsigned bin = (unsigned)(my >> 48);
    unsigned s = suff[(size_t)b * HBINS + bin];
    if (s >= PRE_NMS) return;                          // entire segment beyond cutoff
    unsigned c = binCnt[(size_t)b * HBINS + bin];
    if (s + c > CAND_CAP) c = CAND_CAP - s;
    const u64* seg = cand + (size_t)b * CAND_CAP + s;
    int cnt = 0;
    for (unsigned q = lane; q < c; q += 64)            // coalesced 512B/iter
        cnt += (seg[q] > my) ? 1 : 0;
    #pragma unroll
    for (int off = 32; off; off >>= 1) cnt += __shfl_down(cnt, off, 64);
    int rank = (int)s + __shfl(cnt, 0, 64);
    if (rank < PRE_NMS && lane == 0) {
        int n = (int)(~(unsigned)(my & 0xFFFFFFFFull));
        const float4* anch4 = (const float4*)anchors + (size_t)b * N_ANCHORS;
        const float4* bb4   = (const float4*)bbox    + (size_t)b * N_ANCHORS;
        float4 a  = anch4[n];
        float4 dd = bb4[n];
        float d0 = dd.x * 0.1f, d1 = dd.y * 0.1f;
        float d2 = dd.z * 0.2f, d3 = dd.w * 0.2f;
        float h = a.z - a.x, w = a.w - a.y;
        float cy = a.x + 0.5f * h + d0 * h;
        float cx = a.y + 0.5f * w + d1 * w;
        h = h * expf(d2);
        w = w * expf(d3);
        float y1 = cy - 0.5f * h, x1 = cx - 0.5f * w;
        float y2 = y1 + h,        x2 = x1 + w;
        y1 = fminf(fmaxf(y1, 0.f), 1.f);
        x1 = fminf(fmaxf(x1, 0.f), 1.f);
        y2 = fminf(fmaxf(y2, 0.f), 1.f);
        x2 = fminf(fmaxf(x2, 0.f), 1.f);
        boxes[(size_t)b * PRE_NMS + rank] = make_float4(y1, x1, y2, x2);
    }
}

// Sparse suppression edges: emit (i<j, iou>0.7) pairs; skip tiles fully below diagonal.
__global__ __launch_bounds__(256) void iou_edges(const float4* __restrict__ boxes,
                                                 int* __restrict__ scal,
                                                 unsigned* __restrict__ edges) {
    int c  = blockIdx.x;     // column chunk 0..93
    int rb = blockIdx.y;     // row block 0..23
    int b  = blockIdx.z;
    int rowBase = rb * 256;
    if (rowBase >= (c + 1) * 64) return;     // all rows > all cols -> no i<j pairs
    const float4* bx = boxes + (size_t)b * PRE_NMS;
    __shared__ float4 cb[64];
    __shared__ float  ca[64];
    int t = threadIdx.x;
    if (t < 64) {
        int col = c * 64 + t;
        float4 v = (col < PRE_NMS) ? bx[col] : make_float4(2.f, 2.f, 2.f, 2.f);
        cb[t] = v;
        ca[t] = (v.z - v.x) * (v.w - v.y);
    }
    __syncthreads();
    int i = rowBase + t;
    if (i >= PRE_NMS) return;
    int rel = i - c * 64;
    u64 maskGT = (rel < 0) ? ~0ull : ((rel >= 63) ? 0ull : ~((2ull << rel) - 1ull));
    if (!maskGT) return;
    float4 bi = bx[i];
    float ai = (bi.z - bi.x) * (bi.w - bi.y);
    u64 m = 0ull;
    #pragma unroll
    for (int j = 0; j < 64; ++j) {
        float4 bj = cb[j];
        float iy1 = fmaxf(bi.x, bj.x);
        float ix1 = fmaxf(bi.y, bj.y);
        float iy2 = fminf(bi.z, bj.z);
        float ix2 = fminf(bi.w, bj.w);
        float inter = fmaxf(iy2 - iy1, 0.f) * fmaxf(ix2 - ix1, 0.f);
        float uni = ai + ca[j] - inter;
        // iou > 0.7  <=>  inter > 0.7*uni  (uni>=0; uni==0 -> inter==0 -> false)
        if (inter > 0.7f * uni) m |= (1ull << j);
    }
    m &= maskGT;
    while (m) {                               // rare
        int j = __ffsll((long long)m) - 1;
        m &= m - 1;
        int col = c * 64 + j;
        int pos = atomicAdd(&scal[b * 8 + 5], 1);
        if (pos < EDGE_CAP)
            edges[(size_t)b * EDGE_CAP + pos] = ((unsigned)col << 16) | (unsigned)i;
    }
}

// Exact greedy NMS as fixpoint of S[j] = exists edge (i,j) with i kept.
__global__ __launch_bounds__(256) void nms_fix(const unsigned* __restrict__ edges,
                                               const int* __restrict__ scal,
                                               const float4* __restrict__ boxes,
                                               float4* __restrict__ out) {
    int b = blockIdx.x;
    int t = threadIdx.x;
    int E = scal[b * 8 + 5];
    if (E > EDGE_CAP) E = EDGE_CAP;
    __shared__ u64 S[NCHUNK];
    __shared__ u64 Snew[NCHUNK];
    __shared__ unsigned eL[EDGE_LDS];
    __shared__ int changed;
    __shared__ int pref[NCHUNK];
    __shared__ int totalKept;
    const unsigned* eg = edges + (size_t)b * EDGE_CAP;
    bool staged = (E <= EDGE_LDS);
    if (staged) for (int k = t; k < E; k += 256) eL[k] = eg[k];
    for (int w = t; w < NCHUNK; w += 256) S[w] = 0ull;
    __syncthreads();
    if (E > 0) {
        for (int it = 0; it < PRE_NMS + 1; ++it) {
            for (int w = t; w < NCHUNK; w += 256) Snew[w] = 0ull;
            if (t == 0) changed = 0;
            __syncthreads();
            for (int k = t; k < E; k += 256) {
                unsigned e = staged ? eL[k] : eg[k];
                int i = (int)(e & 0xFFFFu), j = (int)(e >> 16);
                if (!((S[i >> 6] >> (i & 63)) & 1ull))
                    atomicOr(&Snew[j >> 6], 1ull << (j & 63));
            }
            __syncthreads();
            int ch = 0;
            for (int w = t; w < NCHUNK; w += 256) {
                if (Snew[w] != S[w]) { ch = 1; S[w] = Snew[w]; }
            }
            if (ch) changed = 1;
            __syncthreads();
            if (!changed) break;
        }
    }
    for (int w = t; w < NCHUNK; w += 256) {
        u64 valid = (w < NCHUNK - 1) ? ~0ull : ((1ull << (PRE_NMS - (NCHUNK - 1) * 64)) - 1ull);
        Snew[w] = (~S[w]) & valid;            // keep bitset
    }
    __syncthreads();
    if (t == 0) {
        int run = 0;
        for (int w = 0; w < NCHUNK; ++w) { pref[w] = run; run += __popcll(Snew[w]); }
        totalKept = (run < PROPOSALS) ? run : PROPOSALS;
    }
    __syncthreads();
    const float4* bx = boxes + (size_t)b * PRE_NMS;
    float4* ob = out + (size_t)b * PROPOSALS;
    if (t < NCHUNK) {
        u64 k = Snew[t];
        int pos = pref[t];
        while (k && pos < PROPOSALS) {
            int l = __ffsll((long long)k) - 1;
            k &= k - 1;
            ob[pos++] = bx[t * 64 + l];
        }
    }
    int tk = totalKept;
    for (int q = tk + t; q < PROPOSALS; q += 256)
        ob[q] = make_float4(0.f, 0.f, 0.f, 0.f);
}

extern "C" void kernel_launch(void* const* d_in, const int* in_sizes, int n_in,
                              void* d_out, int out_size, void* d_ws, size_t ws_size,
                              hipStream_t stream) {
    (void)in_sizes; (void)n_in; (void)out_size; (void)ws_size;
    const float4* probs4 = (const float4*)d_in[0];
    const float* bbox    = (const float*)d_in[1];
    const float* anchors = (const float*)d_in[2];
    char* ws = (char*)d_ws;
    unsigned* hist   = (unsigned*)(ws + OFF_HIST);
    unsigned* binCnt = (unsigned*)(ws + OFF_BCNT);
    int* scal        = (int*)(ws + OFF_SCAL);
    u64* cand        = (u64*)(ws + OFF_CAND);
    unsigned* suff   = (unsigned*)(ws + OFF_SUFF);
    float4* boxes    = (float4*)(ws + OFF_BOXES);
    unsigned* edges  = (unsigned*)(ws + OFF_EDGES);

    // zero hist + binCnt + counters + cand (graph replays)
    hipMemsetAsync(ws, 0, ZERO_BYTES, stream);

    hist_kernel<<<NB * HB_BLOCKS_PER_B, 256, 0, stream>>>(probs4, hist);
    scan_sel<<<NB, 1024, 0, stream>>>(hist, scal, suff);
    compact<<<NB * CB_BLOCKS_PER_B, 256, 0, stream>>>(probs4, scal, suff, binCnt, cand);
    refine_decode<<<dim3(CAND_CAP / 4, NB), 256, 0, stream>>>(cand, suff, binCnt,
                                                              anchors, bbox, boxes);
    dim3 gIou(NCHUNK, (PRE_NMS + 255) / 256, NB);
    iou_edges<<<gIou, 256, 0, stream>>>(boxes, scal, edges);
    nms_fix<<<NB, 256, 0, stream>>>(edges, scal, boxes, (float4*)d_out);
}